// Round 2
// baseline (2498.245 us; speedup 1.0000x reference)
//
#include <hip/hip_runtime.h>
#include <stdint.h>

#define NCLASS 32000
#define EMB    256
#define NH     512
#define BATCH  128
#define TSEQ   256
#define G4     2048   // 4*NH, gate-interleaved columns: c = 4*j + g (g: 0=f,1=i,2=c,3=o)
#define NGROUP 8      // batch groups (16 rows each)
#define NSLICE 32     // blocks per group (64 gate cols each)
#define GROWS  16

typedef _Float16 f16;
typedef _Float16 half8  __attribute__((ext_vector_type(8)));
typedef _Float16 half4v __attribute__((ext_vector_type(4)));
typedef float    float4v __attribute__((ext_vector_type(4)));

__device__ __forceinline__ float sigm(float x) { return 1.f / (1.f + __expf(-x)); }
__device__ __forceinline__ float ftanh(float x) {
    float a = fabsf(x);
    float e = __expf(2.f * a);
    float r = 1.f - 2.f / (e + 1.f);   // tanh(a), stable for large a (e=inf -> 1)
    return copysignf(r, x);
}

// ---------------- packing kernels ----------------

// WT[c][k] = W_gate[k][j]  (transposed + gate-interleaved, fp16), c = 4j+g
__global__ __launch_bounds__(256) void pack_wT(
    const float* __restrict__ Wf, const float* __restrict__ Wi,
    const float* __restrict__ Wc, const float* __restrict__ Wo,
    f16* __restrict__ WT, int K)
{
    int idx = blockIdx.x * 256 + threadIdx.x;          // over G4*K
    if (idx >= G4 * K) return;
    int c = idx / K, k = idx - c * K;
    int j = c >> 2, g = c & 3;
    const float* W = (g == 0) ? Wf : ((g == 1) ? Wi : ((g == 2) ? Wc : Wo));
    WT[idx] = (f16)W[k * NH + j];
}

__global__ __launch_bounds__(256) void pack_bias(
    const float* __restrict__ bf_, const float* __restrict__ bi_,
    const float* __restrict__ bc_, const float* __restrict__ bo_,
    float* __restrict__ br)
{
    int c = blockIdx.x * 256 + threadIdx.x;
    if (c >= G4) return;
    int j = c >> 2, g = c & 3;
    const float* b = (g == 0) ? bf_ : ((g == 1) ? bi_ : ((g == 2) ? bc_ : bo_));
    br[c] = b[j];
}

// WqT[n][k] = (f16)Whq[k][n]  -- tiled transpose through LDS, both sides coalesced
__global__ __launch_bounds__(256) void transp_whq(
    const float* __restrict__ Whq, f16* __restrict__ WqT)
{
    __shared__ f16 T[64][72];
    int tid = threadIdx.x;
    int nb = blockIdx.x % (NCLASS / 64);
    int kb = blockIdx.x / (NCLASS / 64);
    int n0 = nb * 64, k0 = kb * 64;
    #pragma unroll
    for (int r = 0; r < 16; r++) {
        int id = tid + r * 256;            // 0..4095
        int kr = id >> 6, nc = id & 63;
        T[nc][kr] = (f16)Whq[(size_t)(k0 + kr) * NCLASS + n0 + nc];
    }
    __syncthreads();
    #pragma unroll
    for (int r = 0; r < 2; r++) {
        int id = tid + r * 256;            // 0..511
        int nr = id >> 3, kc = (id & 7) * 8;
        *(half8*)&WqT[(size_t)(n0 + nr) * NH + k0 + kc] = *(half8*)&T[nr][kc];
    }
}

__global__ __launch_bounds__(256) void init_h(
    const float* __restrict__ H, f16* __restrict__ Hh)
{
    int i = blockIdx.x * 256 + threadIdx.x;
    if (i >= BATCH * NH) return;
    Hh[i] = (f16)H[i];
}

__global__ void zero_sync(int* s) { s[threadIdx.x] = 0; }

// ---------------- persistent LSTM recurrence ----------------
// grid = 256 blocks x 256 threads, 1 block/CU (139 KB LDS).
// group g = blockIdx&7 owns batch rows [16g,16g+16); slice s = blockIdx>>3 owns
// gate cols [64s,64s+64) == hidden units [16s,16s+16). C stays in LDS; only H
// (16x16 fp16 per block per step) crosses blocks, via double-buffered global +
// a 32-block generation barrier per group.
__global__ __launch_bounds__(256) void lstm_persist(
    const int* __restrict__ X, const float* __restrict__ E,
    const float* __restrict__ C0,
    const f16* __restrict__ WxT, const f16* __restrict__ WhT,
    const float* __restrict__ bias,
    f16* __restrict__ Hb0, f16* __restrict__ Hb1,
    int* __restrict__ sync)
{
    __shared__ f16   WhS[64][520];       // [col][k], +8 pad -> 2-way bank alias (free)
    __shared__ f16   WxS[64][264];
    __shared__ f16   XeS[2][16][264];    // Xe double buffer
    __shared__ f16   HS[16][520];
    __shared__ float Ps[16][68];
    __shared__ float CS[16][16];

    const int tid  = threadIdx.x;
    const int g    = blockIdx.x & 7;
    const int s    = blockIdx.x >> 3;
    const int b0   = g * GROWS;
    const int c0   = s * 64;
    const int j0   = s * 16;
    const int wave = tid >> 6, lane = tid & 63;
    const int lrow = lane & 15, lhi = lane >> 4;

    int* cnt = sync + g * 32;
    int* gen = sync + g * 32 + 16;

    // ---- one-time staging ----
    #pragma unroll
    for (int r = 0; r < 16; r++) {       // Wh slice: 64 x 512 fp16 (64 KB)
        int id = tid + r * 256;
        int row = id >> 6, ko = (id & 63) * 8;
        *(half8*)&WhS[row][ko] = *(const half8*)(WhT + (size_t)(c0 + row) * NH + ko);
    }
    #pragma unroll
    for (int r = 0; r < 8; r++) {        // Wx slice: 64 x 256 fp16 (32 KB)
        int id = tid + r * 256;
        int row = id >> 5, ko = (id & 31) * 8;
        *(half8*)&WxS[row][ko] = *(const half8*)(WxT + (size_t)(c0 + row) * EMB + ko);
    }
    {                                    // C0 slice
        int b = tid >> 4, jl = tid & 15;
        CS[b][jl] = C0[(size_t)(b0 + b) * NH + j0 + jl];
    }
    const float bv = bias[c0 + wave * 16 + lrow];

    // Xe prefetch helper (inline): gather E rows for step t into slot
    auto prefetch_xe = [&](int t, int slot) {
        #pragma unroll
        for (int r = 0; r < 4; r++) {
            int id = tid + r * 256;          // 0..1023
            int row = id >> 6, k4 = id & 63; // row 0..15, float4 idx 0..63
            int xv = X[(size_t)(b0 + row) * TSEQ + t];
            float4v e = *(const float4v*)(E + (size_t)xv * EMB + k4 * 4);
            half4v h; h[0] = (f16)e[0]; h[1] = (f16)e[1]; h[2] = (f16)e[2]; h[3] = (f16)e[3];
            *(half4v*)&XeS[slot][row][k4 * 4] = h;
        }
    };

    float4v acc0, acc1, acc2, acc3;
    auto mfma_wx = [&](int slot) {       // acc = Xe[slot] @ WxS   (8 MFMAs, 4 chains)
        acc0 = (float4v)0.f; acc1 = (float4v)0.f;
        acc2 = (float4v)0.f; acc3 = (float4v)0.f;
        const f16(*xp)[264] = XeS[slot];
        #pragma unroll
        for (int kk = 0; kk < EMB; kk += 128) {
            half8 a0 = *(const half8*)&xp[lrow][kk      + lhi * 8];
            half8 w0 = *(const half8*)&WxS[wave * 16 + lrow][kk      + lhi * 8];
            half8 a1 = *(const half8*)&xp[lrow][kk + 32 + lhi * 8];
            half8 w1 = *(const half8*)&WxS[wave * 16 + lrow][kk + 32 + lhi * 8];
            half8 a2 = *(const half8*)&xp[lrow][kk + 64 + lhi * 8];
            half8 w2 = *(const half8*)&WxS[wave * 16 + lrow][kk + 64 + lhi * 8];
            half8 a3 = *(const half8*)&xp[lrow][kk + 96 + lhi * 8];
            half8 w3 = *(const half8*)&WxS[wave * 16 + lrow][kk + 96 + lhi * 8];
            acc0 = __builtin_amdgcn_mfma_f32_16x16x32_f16(a0, w0, acc0, 0, 0, 0);
            acc1 = __builtin_amdgcn_mfma_f32_16x16x32_f16(a1, w1, acc1, 0, 0, 0);
            acc2 = __builtin_amdgcn_mfma_f32_16x16x32_f16(a2, w2, acc2, 0, 0, 0);
            acc3 = __builtin_amdgcn_mfma_f32_16x16x32_f16(a3, w3, acc3, 0, 0, 0);
        }
    };

    prefetch_xe(0, 0);
    __syncthreads();
    mfma_wx(0);                          // pre-acc for t=0
    prefetch_xe(1, 1);

    for (int t = 0; t < TSEQ; t++) {
        // ---- wait for H_t (published by step t-1) ----
        if (tid == 0 && t > 0) {
            while (__hip_atomic_load(gen, __ATOMIC_ACQUIRE, __HIP_MEMORY_SCOPE_AGENT) < t)
                __builtin_amdgcn_s_sleep(1);
        }
        __syncthreads();

        // ---- stage H_t (16 rows x 512) into LDS ----
        const f16* hsrc = (t & 1) ? Hb1 : Hb0;
        #pragma unroll
        for (int r = 0; r < 4; r++) {
            int id = tid + r * 256;
            int row = id >> 6, ko = (id & 63) * 8;
            *(half8*)&HS[row][ko] = *(const half8*)(hsrc + (size_t)(b0 + row) * NH + ko);
        }
        __syncthreads();

        // ---- gates += H_t @ WhS  (16 MFMAs, 4 chains; acc pre-holds Xe@Wx) ----
        #pragma unroll
        for (int kk = 0; kk < NH; kk += 128) {
            half8 a0 = *(const half8*)&HS[lrow][kk      + lhi * 8];
            half8 w0 = *(const half8*)&WhS[wave * 16 + lrow][kk      + lhi * 8];
            half8 a1 = *(const half8*)&HS[lrow][kk + 32 + lhi * 8];
            half8 w1 = *(const half8*)&WhS[wave * 16 + lrow][kk + 32 + lhi * 8];
            half8 a2 = *(const half8*)&HS[lrow][kk + 64 + lhi * 8];
            half8 w2 = *(const half8*)&WhS[wave * 16 + lrow][kk + 64 + lhi * 8];
            half8 a3 = *(const half8*)&HS[lrow][kk + 96 + lhi * 8];
            half8 w3 = *(const half8*)&WhS[wave * 16 + lrow][kk + 96 + lhi * 8];
            acc0 = __builtin_amdgcn_mfma_f32_16x16x32_f16(a0, w0, acc0, 0, 0, 0);
            acc1 = __builtin_amdgcn_mfma_f32_16x16x32_f16(a1, w1, acc1, 0, 0, 0);
            acc2 = __builtin_amdgcn_mfma_f32_16x16x32_f16(a2, w2, acc2, 0, 0, 0);
            acc3 = __builtin_amdgcn_mfma_f32_16x16x32_f16(a3, w3, acc3, 0, 0, 0);
        }
        {
            float4v ssum = acc0 + acc1 + acc2 + acc3;
            #pragma unroll
            for (int r = 0; r < 4; r++)
                Ps[lhi * 4 + r][wave * 16 + lrow] = ssum[r] + bv;
        }
        __syncthreads();

        // ---- elementwise gate math; C stays in LDS; write H_{t+1} slice ----
        {
            int b = tid >> 4, jl = tid & 15;
            float pf = Ps[b][jl * 4 + 0];
            float pi = Ps[b][jl * 4 + 1];
            float pc = Ps[b][jl * 4 + 2];
            float po = Ps[b][jl * 4 + 3];
            float F  = sigm(pf);
            float I  = sigm(pi);
            float Ct = ftanh(pc);
            float O  = sigm(po);
            float cOld = CS[b][jl];
            float Hn   = O * ftanh(cOld);          // OLD C (matches reference)
            CS[b][jl]  = F * cOld + I * Ct;
            f16* hdst = ((t + 1) & 1) ? Hb1 : Hb0;
            hdst[(size_t)(b0 + b) * NH + j0 + jl] = (f16)Hn;
        }
        __syncthreads();   // drains all threads' H stores (vmcnt) before release

        // ---- arrive: publish H_{t+1} (monotonic generation barrier) ----
        if (tid == 0) {
            int a = __hip_atomic_fetch_add(cnt, 1, __ATOMIC_ACQ_REL, __HIP_MEMORY_SCOPE_AGENT);
            if (a == NSLICE * (t + 1) - 1)
                __hip_atomic_store(gen, t + 1, __ATOMIC_RELEASE, __HIP_MEMORY_SCOPE_AGENT);
        }

        // ---- hidden in barrier slack: pre-acc Wx-part of t+1, prefetch Xe[t+2] ----
        if (t + 1 < TSEQ) {
            mfma_wx((t + 1) & 1);
            if (t + 2 < TSEQ) prefetch_xe(t + 2, t & 1);
        }
    }
}

// ---------------- out = H @ Whq + bq  (M=128, N=32000, K=512) ----------------
__global__ __launch_bounds__(256) void gemm_out(
    const f16* __restrict__ Hh, const f16* __restrict__ WqT,
    const float* __restrict__ bq, float* __restrict__ out)
{
    __shared__ f16 As[128][40];
    __shared__ f16 BsT[64][40];
    int tid = threadIdx.x, wave = tid >> 6, lane = tid & 63;
    int lrow = lane & 15, lhi = lane >> 4;
    int col0 = blockIdx.x * 64;

    float4v acc[2][4];
    #pragma unroll
    for (int m = 0; m < 2; m++)
        #pragma unroll
        for (int j = 0; j < 4; j++) acc[m][j] = (float4v)0.f;

    int ar = tid >> 1, ako = (tid & 1) * 16;
    int br = tid >> 2, bko = (tid & 3) * 8;
    for (int kk = 0; kk < NH; kk += 32) {
        *(half8*)&As[ar][ako]     = *(const half8*)(Hh + (size_t)ar * NH + kk + ako);
        *(half8*)&As[ar][ako + 8] = *(const half8*)(Hh + (size_t)ar * NH + kk + ako + 8);
        *(half8*)&BsT[br][bko]    = *(const half8*)(WqT + (size_t)(col0 + br) * NH + kk + bko);
        __syncthreads();
        half8 af[2];
        #pragma unroll
        for (int m = 0; m < 2; m++)
            af[m] = *(const half8*)&As[wave * 32 + m * 16 + lrow][lhi * 8];
        #pragma unroll
        for (int j = 0; j < 4; j++) {
            half8 bfr = *(const half8*)&BsT[j * 16 + lrow][lhi * 8];
            #pragma unroll
            for (int m = 0; m < 2; m++)
                acc[m][j] = __builtin_amdgcn_mfma_f32_16x16x32_f16(af[m], bfr, acc[m][j], 0, 0, 0);
        }
        __syncthreads();
    }
    #pragma unroll
    for (int m = 0; m < 2; m++)
        #pragma unroll
        for (int j = 0; j < 4; j++) {
            int col = col0 + j * 16 + lrow;
            float bqv = bq[col];
            #pragma unroll
            for (int r = 0; r < 4; r++) {
                int row = wave * 32 + m * 16 + lhi * 4 + r;
                out[(size_t)row * NCLASS + col] = acc[m][j][r] + bqv;
            }
        }
}

// ---------------- launch ----------------
extern "C" void kernel_launch(void* const* d_in, const int* in_sizes, int n_in,
                              void* d_out, int out_size, void* d_ws, size_t ws_size,
                              hipStream_t stream)
{
    (void)in_sizes; (void)n_in; (void)out_size;
    const int*   X   = (const int*)  d_in[0];
    const float* H0  = (const float*)d_in[1];
    const float* C0  = (const float*)d_in[2];
    const float* E   = (const float*)d_in[3];
    const float* Wxf = (const float*)d_in[4];
    const float* Whf = (const float*)d_in[5];
    const float* bf_ = (const float*)d_in[6];
    const float* Wxi = (const float*)d_in[7];
    const float* Whi = (const float*)d_in[8];
    const float* bi_ = (const float*)d_in[9];
    const float* Wxc = (const float*)d_in[10];
    const float* Whc = (const float*)d_in[11];
    const float* bc_ = (const float*)d_in[12];
    const float* Wxo = (const float*)d_in[13];
    const float* Who = (const float*)d_in[14];
    const float* bo_ = (const float*)d_in[15];
    const float* Whq = (const float*)d_in[16];
    const float* bq  = (const float*)d_in[17];

    char* ws = (char*)d_ws;
    size_t o = 0;
    auto alloc = [&](size_t bytes) {
        size_t r = o;
        o = (o + bytes + 255) & ~(size_t)255;
        return r;
    };
    f16*   WxT  = (f16*)  (ws + alloc((size_t)G4 * EMB * 2));
    f16*   WhT  = (f16*)  (ws + alloc((size_t)G4 * NH * 2));
    float* bias = (float*)(ws + alloc((size_t)G4 * 4));
    f16*   WqT  = (f16*)  (ws + alloc((size_t)NH * NCLASS * 2));
    f16*   Hb0  = (f16*)  (ws + alloc((size_t)BATCH * NH * 2));
    f16*   Hb1  = (f16*)  (ws + alloc((size_t)BATCH * NH * 2));
    int*   sync = (int*)  (ws + alloc(256 * 4));
    if (o > ws_size) return;   // insufficient workspace -> clean validation failure

    pack_wT  <<<(G4 * EMB + 255) / 256, 256, 0, stream>>>(Wxf, Wxi, Wxc, Wxo, WxT, EMB);
    pack_wT  <<<(G4 * NH  + 255) / 256, 256, 0, stream>>>(Whf, Whi, Whc, Who, WhT, NH);
    pack_bias<<<(G4 + 255) / 256,       256, 0, stream>>>(bf_, bi_, bc_, bo_, bias);
    transp_whq<<<(NCLASS / 64) * (NH / 64), 256, 0, stream>>>(Whq, WqT);
    init_h   <<<(BATCH * NH + 255) / 256, 256, 0, stream>>>(H0, Hb0);
    zero_sync<<<1, 256, 0, stream>>>(sync);

    lstm_persist<<<256, 256, 0, stream>>>(X, E, C0, WxT, WhT, bias, Hb0, Hb1, sync);

    // T=256 even -> final H is in Hb0
    gemm_out<<<NCLASS / 64, 256, 0, stream>>>(Hb0, WqT, bq, (float*)d_out);
}

// Round 3
// 1148.761 us; speedup vs baseline: 2.1747x; 2.1747x over previous
//
#include <hip/hip_runtime.h>
#include <stdint.h>

#define NCLASS 32000
#define EMB    256
#define NH     512
#define BATCH  128
#define TSEQ   256
#define G4     2048   // 4*NH, gate-interleaved columns: c = 4*j + g (g: 0=f,1=i,2=c,3=o)
#define NGROUP 8      // batch groups (16 rows each)
#define NSLICE 32     // blocks per group (64 gate cols each)
#define GROWS  16

typedef _Float16 f16;
typedef _Float16 half8  __attribute__((ext_vector_type(8)));
typedef _Float16 half4v __attribute__((ext_vector_type(4)));
typedef float    float4v __attribute__((ext_vector_type(4)));

__device__ __forceinline__ float sigm(float x) { return 1.f / (1.f + __expf(-x)); }
__device__ __forceinline__ float ftanh(float x) {
    float a = fabsf(x);
    float e = __expf(2.f * a);
    float r = 1.f - 2.f / (e + 1.f);   // tanh(a), stable for large a (e=inf -> 1)
    return copysignf(r, x);
}

// ---------------- packing kernels ----------------

// WT[c][k] = W_gate[k][j]  (transposed + gate-interleaved, fp16), c = 4j+g
__global__ __launch_bounds__(256) void pack_wT(
    const float* __restrict__ Wf, const float* __restrict__ Wi,
    const float* __restrict__ Wc, const float* __restrict__ Wo,
    f16* __restrict__ WT, int K)
{
    int idx = blockIdx.x * 256 + threadIdx.x;          // over G4*K
    if (idx >= G4 * K) return;
    int c = idx / K, k = idx - c * K;
    int j = c >> 2, g = c & 3;
    const float* W = (g == 0) ? Wf : ((g == 1) ? Wi : ((g == 2) ? Wc : Wo));
    WT[idx] = (f16)W[k * NH + j];
}

__global__ __launch_bounds__(256) void pack_bias(
    const float* __restrict__ bf_, const float* __restrict__ bi_,
    const float* __restrict__ bc_, const float* __restrict__ bo_,
    float* __restrict__ br)
{
    int c = blockIdx.x * 256 + threadIdx.x;
    if (c >= G4) return;
    int j = c >> 2, g = c & 3;
    const float* b = (g == 0) ? bf_ : ((g == 1) ? bi_ : ((g == 2) ? bc_ : bo_));
    br[c] = b[j];
}

// WqT[n][k] = (f16)Whq[k][n]  -- tiled transpose through LDS, both sides coalesced
__global__ __launch_bounds__(256) void transp_whq(
    const float* __restrict__ Whq, f16* __restrict__ WqT)
{
    __shared__ f16 T[64][72];
    int tid = threadIdx.x;
    int nb = blockIdx.x % (NCLASS / 64);
    int kb = blockIdx.x / (NCLASS / 64);
    int n0 = nb * 64, k0 = kb * 64;
    #pragma unroll
    for (int r = 0; r < 16; r++) {
        int id = tid + r * 256;            // 0..4095
        int kr = id >> 6, nc = id & 63;
        T[nc][kr] = (f16)Whq[(size_t)(k0 + kr) * NCLASS + n0 + nc];
    }
    __syncthreads();
    #pragma unroll
    for (int r = 0; r < 2; r++) {
        int id = tid + r * 256;            // 0..511
        int nr = id >> 3, kc = (id & 7) * 8;
        *(half8*)&WqT[(size_t)(n0 + nr) * NH + k0 + kc] = *(half8*)&T[nr][kc];
    }
}

__global__ __launch_bounds__(256) void init_h(
    const float* __restrict__ H, f16* __restrict__ Hh)
{
    int i = blockIdx.x * 256 + threadIdx.x;
    if (i >= BATCH * NH) return;
    Hh[i] = (f16)H[i];
}

__global__ void zero_sync(int* s) { s[threadIdx.x] = 0; }

// ---------------- persistent LSTM recurrence ----------------
// grid = 256 blocks x 256 threads, 1 block/CU (139 KB LDS).
// group g = blockIdx&7 owns batch rows [16g,16g+16); slice s = blockIdx>>3 owns
// gate cols [64s,64s+64) == hidden units [16s,16s+16). C stays in LDS.
// Cross-block H exchange is 100% fence-free: H and per-block generation flags
// travel as RELAXED/AGENT (sc1, LLC-coherent) accesses; ordering comes from
// __syncthreads' vmcnt(0) drain before the flag store. No wbl2/inv storms.
__global__ __launch_bounds__(256) void lstm_persist(
    const int* __restrict__ X, const float* __restrict__ E,
    const float* __restrict__ C0,
    const f16* __restrict__ WxT, const f16* __restrict__ WhT,
    const float* __restrict__ bias,
    f16* __restrict__ Hb0, f16* __restrict__ Hb1,
    int* __restrict__ sync)
{
    __shared__ f16   WhS[64][520];       // [col][k]
    __shared__ f16   WxS[64][264];
    __shared__ f16   XeS[2][16][264];    // Xe double buffer
    __shared__ f16   HS[16][520];
    __shared__ float Ps[16][68];
    __shared__ float CS[16][16];

    const int tid  = threadIdx.x;
    const int g    = blockIdx.x & 7;
    const int s    = blockIdx.x >> 3;
    const int b0   = g * GROWS;
    const int c0   = s * 64;
    const int j0   = s * 16;
    const int wave = tid >> 6, lane = tid & 63;
    const int lrow = lane & 15, lhi = lane >> 4;

    int* flags = sync + g * NSLICE;      // one generation flag per slice-block

    // ---- one-time staging ----
    #pragma unroll
    for (int r = 0; r < 16; r++) {       // Wh slice: 64 x 512 fp16 (64 KB)
        int id = tid + r * 256;
        int row = id >> 6, ko = (id & 63) * 8;
        *(half8*)&WhS[row][ko] = *(const half8*)(WhT + (size_t)(c0 + row) * NH + ko);
    }
    #pragma unroll
    for (int r = 0; r < 8; r++) {        // Wx slice: 64 x 256 fp16 (32 KB)
        int id = tid + r * 256;
        int row = id >> 5, ko = (id & 31) * 8;
        *(half8*)&WxS[row][ko] = *(const half8*)(WxT + (size_t)(c0 + row) * EMB + ko);
    }
    {                                    // C0 slice
        int b = tid >> 4, jl = tid & 15;
        CS[b][jl] = C0[(size_t)(b0 + b) * NH + j0 + jl];
    }
    const float bv = bias[c0 + wave * 16 + lrow];

    // Xe prefetch helper: gather E rows for step t into slot
    auto prefetch_xe = [&](int t, int slot) {
        #pragma unroll
        for (int r = 0; r < 4; r++) {
            int id = tid + r * 256;          // 0..1023
            int row = id >> 6, k4 = id & 63; // row 0..15, float4 idx 0..63
            int xv = X[(size_t)(b0 + row) * TSEQ + t];
            float4v e = *(const float4v*)(E + (size_t)xv * EMB + k4 * 4);
            half4v h; h[0] = (f16)e[0]; h[1] = (f16)e[1]; h[2] = (f16)e[2]; h[3] = (f16)e[3];
            *(half4v*)&XeS[slot][row][k4 * 4] = h;
        }
    };

    float4v acc0, acc1, acc2, acc3;
    auto mfma_wx = [&](int slot) {       // acc = Xe[slot] @ WxS   (8 MFMAs, 4 chains)
        acc0 = (float4v)0.f; acc1 = (float4v)0.f;
        acc2 = (float4v)0.f; acc3 = (float4v)0.f;
        const f16(*xp)[264] = XeS[slot];
        #pragma unroll
        for (int kk = 0; kk < EMB; kk += 128) {
            half8 a0 = *(const half8*)&xp[lrow][kk      + lhi * 8];
            half8 w0 = *(const half8*)&WxS[wave * 16 + lrow][kk      + lhi * 8];
            half8 a1 = *(const half8*)&xp[lrow][kk + 32 + lhi * 8];
            half8 w1 = *(const half8*)&WxS[wave * 16 + lrow][kk + 32 + lhi * 8];
            half8 a2 = *(const half8*)&xp[lrow][kk + 64 + lhi * 8];
            half8 w2 = *(const half8*)&WxS[wave * 16 + lrow][kk + 64 + lhi * 8];
            half8 a3 = *(const half8*)&xp[lrow][kk + 96 + lhi * 8];
            half8 w3 = *(const half8*)&WxS[wave * 16 + lrow][kk + 96 + lhi * 8];
            acc0 = __builtin_amdgcn_mfma_f32_16x16x32_f16(a0, w0, acc0, 0, 0, 0);
            acc1 = __builtin_amdgcn_mfma_f32_16x16x32_f16(a1, w1, acc1, 0, 0, 0);
            acc2 = __builtin_amdgcn_mfma_f32_16x16x32_f16(a2, w2, acc2, 0, 0, 0);
            acc3 = __builtin_amdgcn_mfma_f32_16x16x32_f16(a3, w3, acc3, 0, 0, 0);
        }
    };

    prefetch_xe(0, 0);
    __syncthreads();
    mfma_wx(0);                          // pre-acc for t=0
    prefetch_xe(1, 1);

    for (int t = 0; t < TSEQ; t++) {
        // ---- wait until every block in the group has published H_t ----
        if (wave == 0) {
            int f;
            do {
                f = (lane < NSLICE)
                    ? __hip_atomic_load(&flags[lane], __ATOMIC_RELAXED, __HIP_MEMORY_SCOPE_AGENT)
                    : t;
            } while (!__all(f >= t));
        }
        __syncthreads();

        // ---- stage H_t (16 rows x 512) into LDS via LLC-coherent u64 loads ----
        const uint64_t* hsrc = (const uint64_t*)((t & 1) ? Hb1 : Hb0);
        #pragma unroll
        for (int r = 0; r < 8; r++) {
            int id = tid + r * 256;          // 0..2047
            int row = id >> 7, qc = id & 127;
            uint64_t v = __hip_atomic_load(hsrc + (size_t)(b0 + row) * (NH / 4) + qc,
                                           __ATOMIC_RELAXED, __HIP_MEMORY_SCOPE_AGENT);
            *(uint64_t*)((char*)&HS[row][0] + (size_t)qc * 8) = v;
        }
        __syncthreads();

        // ---- gates += H_t @ WhS  (16 MFMAs, 4 chains; acc pre-holds Xe@Wx) ----
        #pragma unroll
        for (int kk = 0; kk < NH; kk += 128) {
            half8 a0 = *(const half8*)&HS[lrow][kk      + lhi * 8];
            half8 w0 = *(const half8*)&WhS[wave * 16 + lrow][kk      + lhi * 8];
            half8 a1 = *(const half8*)&HS[lrow][kk + 32 + lhi * 8];
            half8 w1 = *(const half8*)&WhS[wave * 16 + lrow][kk + 32 + lhi * 8];
            half8 a2 = *(const half8*)&HS[lrow][kk + 64 + lhi * 8];
            half8 w2 = *(const half8*)&WhS[wave * 16 + lrow][kk + 64 + lhi * 8];
            half8 a3 = *(const half8*)&HS[lrow][kk + 96 + lhi * 8];
            half8 w3 = *(const half8*)&WhS[wave * 16 + lrow][kk + 96 + lhi * 8];
            acc0 = __builtin_amdgcn_mfma_f32_16x16x32_f16(a0, w0, acc0, 0, 0, 0);
            acc1 = __builtin_amdgcn_mfma_f32_16x16x32_f16(a1, w1, acc1, 0, 0, 0);
            acc2 = __builtin_amdgcn_mfma_f32_16x16x32_f16(a2, w2, acc2, 0, 0, 0);
            acc3 = __builtin_amdgcn_mfma_f32_16x16x32_f16(a3, w3, acc3, 0, 0, 0);
        }
        {
            float4v ssum = acc0 + acc1 + acc2 + acc3;
            #pragma unroll
            for (int r = 0; r < 4; r++)
                Ps[lhi * 4 + r][wave * 16 + lrow] = ssum[r] + bv;
        }
        __syncthreads();

        // ---- gate math (2 hidden units/thread); C stays in LDS; pack+store H ----
        if (tid < 128) {
            int b = tid >> 3, j2 = (tid & 7) * 2;
            float pf0 = Ps[b][j2 * 4 + 0], pi0 = Ps[b][j2 * 4 + 1];
            float pc0 = Ps[b][j2 * 4 + 2], po0 = Ps[b][j2 * 4 + 3];
            float pf1 = Ps[b][j2 * 4 + 4], pi1 = Ps[b][j2 * 4 + 5];
            float pc1 = Ps[b][j2 * 4 + 6], po1 = Ps[b][j2 * 4 + 7];
            float cA = CS[b][j2], cB = CS[b][j2 + 1];
            float Hn0 = sigm(po0) * ftanh(cA);     // OLD C (matches reference)
            float Hn1 = sigm(po1) * ftanh(cB);
            CS[b][j2]     = sigm(pf0) * cA + sigm(pi0) * ftanh(pc0);
            CS[b][j2 + 1] = sigm(pf1) * cB + sigm(pi1) * ftanh(pc1);
            union { f16 h[2]; uint32_t u; } pk;
            pk.h[0] = (f16)Hn0; pk.h[1] = (f16)Hn1;
            f16* hb = ((t + 1) & 1) ? Hb1 : Hb0;
            uint32_t* hdst = (uint32_t*)(hb + (size_t)(b0 + b) * NH + j0 + j2);
            __hip_atomic_store(hdst, pk.u, __ATOMIC_RELAXED, __HIP_MEMORY_SCOPE_AGENT);
        }
        __syncthreads();   // vmcnt(0) drain of ALL waves' sc1 H stores

        // ---- publish: flag store reaches LLC strictly after the H data ----
        if (tid == 0)
            __hip_atomic_store(&flags[s], t + 1, __ATOMIC_RELAXED, __HIP_MEMORY_SCOPE_AGENT);

        // ---- hidden in barrier slack: pre-acc Wx-part of t+1, prefetch Xe[t+2] ----
        if (t + 1 < TSEQ) {
            mfma_wx((t + 1) & 1);
            if (t + 2 < TSEQ) prefetch_xe(t + 2, t & 1);
        }
    }
}

// ---------------- out = H @ Whq + bq  (M=128, N=32000, K=512) ----------------
__global__ __launch_bounds__(256) void gemm_out(
    const f16* __restrict__ Hh, const f16* __restrict__ WqT,
    const float* __restrict__ bq, float* __restrict__ out)
{
    __shared__ f16 As[128][40];
    __shared__ f16 BsT[64][40];
    int tid = threadIdx.x, wave = tid >> 6, lane = tid & 63;
    int lrow = lane & 15, lhi = lane >> 4;
    int col0 = blockIdx.x * 64;

    float4v acc[2][4];
    #pragma unroll
    for (int m = 0; m < 2; m++)
        #pragma unroll
        for (int j = 0; j < 4; j++) acc[m][j] = (float4v)0.f;

    int ar = tid >> 1, ako = (tid & 1) * 16;
    int br = tid >> 2, bko = (tid & 3) * 8;
    for (int kk = 0; kk < NH; kk += 32) {
        *(half8*)&As[ar][ako]     = *(const half8*)(Hh + (size_t)ar * NH + kk + ako);
        *(half8*)&As[ar][ako + 8] = *(const half8*)(Hh + (size_t)ar * NH + kk + ako + 8);
        *(half8*)&BsT[br][bko]    = *(const half8*)(WqT + (size_t)(col0 + br) * NH + kk + bko);
        __syncthreads();
        half8 af[2];
        #pragma unroll
        for (int m = 0; m < 2; m++)
            af[m] = *(const half8*)&As[wave * 32 + m * 16 + lrow][lhi * 8];
        #pragma unroll
        for (int j = 0; j < 4; j++) {
            half8 bfr = *(const half8*)&BsT[j * 16 + lrow][lhi * 8];
            #pragma unroll
            for (int m = 0; m < 2; m++)
                acc[m][j] = __builtin_amdgcn_mfma_f32_16x16x32_f16(af[m], bfr, acc[m][j], 0, 0, 0);
        }
        __syncthreads();
    }
    #pragma unroll
    for (int m = 0; m < 2; m++)
        #pragma unroll
        for (int j = 0; j < 4; j++) {
            int col = col0 + j * 16 + lrow;
            float bqv = bq[col];
            #pragma unroll
            for (int r = 0; r < 4; r++) {
                int row = wave * 32 + m * 16 + lhi * 4 + r;
                out[(size_t)row * NCLASS + col] = acc[m][j][r] + bqv;
            }
        }
}

// ---------------- launch ----------------
extern "C" void kernel_launch(void* const* d_in, const int* in_sizes, int n_in,
                              void* d_out, int out_size, void* d_ws, size_t ws_size,
                              hipStream_t stream)
{
    (void)in_sizes; (void)n_in; (void)out_size;
    const int*   X   = (const int*)  d_in[0];
    const float* H0  = (const float*)d_in[1];
    const float* C0  = (const float*)d_in[2];
    const float* E   = (const float*)d_in[3];
    const float* Wxf = (const float*)d_in[4];
    const float* Whf = (const float*)d_in[5];
    const float* bf_ = (const float*)d_in[6];
    const float* Wxi = (const float*)d_in[7];
    const float* Whi = (const float*)d_in[8];
    const float* bi_ = (const float*)d_in[9];
    const float* Wxc = (const float*)d_in[10];
    const float* Whc = (const float*)d_in[11];
    const float* bc_ = (const float*)d_in[12];
    const float* Wxo = (const float*)d_in[13];
    const float* Who = (const float*)d_in[14];
    const float* bo_ = (const float*)d_in[15];
    const float* Whq = (const float*)d_in[16];
    const float* bq  = (const float*)d_in[17];

    char* ws = (char*)d_ws;
    size_t o = 0;
    auto alloc = [&](size_t bytes) {
        size_t r = o;
        o = (o + bytes + 255) & ~(size_t)255;
        return r;
    };
    f16*   WxT  = (f16*)  (ws + alloc((size_t)G4 * EMB * 2));
    f16*   WhT  = (f16*)  (ws + alloc((size_t)G4 * NH * 2));
    float* bias = (float*)(ws + alloc((size_t)G4 * 4));
    f16*   WqT  = (f16*)  (ws + alloc((size_t)NH * NCLASS * 2));
    f16*   Hb0  = (f16*)  (ws + alloc((size_t)BATCH * NH * 2));
    f16*   Hb1  = (f16*)  (ws + alloc((size_t)BATCH * NH * 2));
    int*   sync = (int*)  (ws + alloc(256 * 4));
    if (o > ws_size) return;   // insufficient workspace -> clean validation failure

    pack_wT  <<<(G4 * EMB + 255) / 256, 256, 0, stream>>>(Wxf, Wxi, Wxc, Wxo, WxT, EMB);
    pack_wT  <<<(G4 * NH  + 255) / 256, 256, 0, stream>>>(Whf, Whi, Whc, Who, WhT, NH);
    pack_bias<<<(G4 + 255) / 256,       256, 0, stream>>>(bf_, bi_, bc_, bo_, bias);
    transp_whq<<<(NCLASS / 64) * (NH / 64), 256, 0, stream>>>(Whq, WqT);
    init_h   <<<(BATCH * NH + 255) / 256, 256, 0, stream>>>(H0, Hb0);
    zero_sync<<<1, 256, 0, stream>>>(sync);

    lstm_persist<<<256, 256, 0, stream>>>(X, E, C0, WxT, WhT, bias, Hb0, Hb1, sync);

    // T=256 even -> final H is in Hb0
    gemm_out<<<NCLASS / 64, 256, 0, stream>>>(Hb0, WqT, bq, (float*)d_out);
}

// Round 5
// 669.568 us; speedup vs baseline: 3.7311x; 1.7157x over previous
//
#include <hip/hip_runtime.h>
#include <stdint.h>

#define NCLASS 32000
#define EMB    256
#define NH     512
#define BATCH  128
#define TSEQ   256
#define G4     2048   // 4*NH, gate-interleaved columns: c = 4*j + g (g: 0=f,1=i,2=c,3=o)
#define NGROUP 8      // batch groups == XCDs (16 rows each)
#define NSLICE 32     // blocks per group (64 gate cols each)
#define GROWS  16

typedef _Float16 f16;
typedef _Float16 half8  __attribute__((ext_vector_type(8)));
typedef _Float16 half4v __attribute__((ext_vector_type(4)));
typedef float    float4v __attribute__((ext_vector_type(4)));

__device__ __forceinline__ float sigm(float x) { return 1.f / (1.f + __expf(-x)); }
__device__ __forceinline__ float ftanh(float x) {
    float a = fabsf(x);
    float e = __expf(2.f * a);
    float r = 1.f - 2.f / (e + 1.f);   // tanh(a), stable for large a (e=inf -> 1)
    return copysignf(r, x);
}

// sc0 = L1-bypass, L2-coherent (intra-XCD). Manual vmcnt per rule #18.
#define GLOAD64_SC0(dst, ap) asm volatile("global_load_dwordx2 %0, %1, off sc0" : "=v"(dst) : "v"(ap))
#define GLOAD32_SC0(dst, ap) asm volatile("global_load_dword %0, %1, off sc0" : "=v"(dst) : "v"(ap))
#define GSTORE32_SC0(ap, val) asm volatile("global_store_dword %0, %1, off sc0" :: "v"(ap), "v"(val) : "memory")
#define WAITVM0() asm volatile("s_waitcnt vmcnt(0)" ::: "memory")

// ---------------- packing kernels ----------------

// WT[c][k] = W_gate[k][j]  (transposed + gate-interleaved, fp16), c = 4j+g
__global__ __launch_bounds__(256) void pack_wT(
    const float* __restrict__ Wf, const float* __restrict__ Wi,
    const float* __restrict__ Wc, const float* __restrict__ Wo,
    f16* __restrict__ WT, int K)
{
    int idx = blockIdx.x * 256 + threadIdx.x;          // over G4*K
    if (idx >= G4 * K) return;
    int c = idx / K, k = idx - c * K;
    int j = c >> 2, g = c & 3;
    const float* W = (g == 0) ? Wf : ((g == 1) ? Wi : ((g == 2) ? Wc : Wo));
    WT[idx] = (f16)W[k * NH + j];
}

__global__ __launch_bounds__(256) void pack_bias(
    const float* __restrict__ bf_, const float* __restrict__ bi_,
    const float* __restrict__ bc_, const float* __restrict__ bo_,
    float* __restrict__ br)
{
    int c = blockIdx.x * 256 + threadIdx.x;
    if (c >= G4) return;
    int j = c >> 2, g = c & 3;
    const float* b = (g == 0) ? bf_ : ((g == 1) ? bi_ : ((g == 2) ? bc_ : bo_));
    br[c] = b[j];
}

// WqT[n][k] = (f16)Whq[k][n]  -- tiled transpose through LDS, both sides coalesced
__global__ __launch_bounds__(256) void transp_whq(
    const float* __restrict__ Whq, f16* __restrict__ WqT)
{
    __shared__ f16 T[64][72];
    int tid = threadIdx.x;
    int nb = blockIdx.x % (NCLASS / 64);
    int kb = blockIdx.x / (NCLASS / 64);
    int n0 = nb * 64, k0 = kb * 64;
    #pragma unroll
    for (int r = 0; r < 16; r++) {
        int id = tid + r * 256;            // 0..4095
        int kr = id >> 6, nc = id & 63;
        T[nc][kr] = (f16)Whq[(size_t)(k0 + kr) * NCLASS + n0 + nc];
    }
    __syncthreads();
    #pragma unroll
    for (int r = 0; r < 2; r++) {
        int id = tid + r * 256;            // 0..511
        int nr = id >> 3, kc = (id & 7) * 8;
        *(half8*)&WqT[(size_t)(n0 + nr) * NH + k0 + kc] = *(half8*)&T[nr][kc];
    }
}

__global__ __launch_bounds__(256) void init_h(
    const float* __restrict__ H, f16* __restrict__ Hh)
{
    int i = blockIdx.x * 256 + threadIdx.x;
    if (i >= BATCH * NH) return;
    Hh[i] = (f16)H[i];
}

__global__ void zero_sync(int* s) { s[threadIdx.x] = 0; s[threadIdx.x + 256] = 0; }

// ---------------- persistent LSTM recurrence ----------------
// grid = 256 blocks x 256 threads, 1 block/CU (134 KB LDS => pigeonhole: exactly
// 32 blocks per XCD). Blocks self-assemble into groups by physical XCC_ID, so a
// group's 32 blocks provably share one XCD L2 -> all H/flag exchange uses
// sc0-only accesses (L1 bypass, L2-coherent), never leaving the XCD.
//
// SYNC LAYOUT (the round-4 deadlock fix): per-XCD L2s are NOT coherent, so no
// 128-B cache line may ever be written by two XCDs (dirty-writeback clobbering
// in the IF$ permanently loses flag updates -> deadlock). Layout:
//   sync[g*32 + s]      : generation flag of (group g, slice s) -- group g's 32
//                         flags occupy EXACTLY one exclusive 128-B line.
//   sync[256 + g*32]    : claim counter of group g -- one exclusive line each.
__global__ __launch_bounds__(256) void lstm_persist(
    const int* __restrict__ X, const float* __restrict__ E,
    const float* __restrict__ C0,
    const f16* __restrict__ WxT, const f16* __restrict__ WhT,
    const float* __restrict__ bias,
    f16* __restrict__ Hb0, f16* __restrict__ Hb1,
    int* __restrict__ sync)
{
    __shared__ f16 WhS[64][520];       // [col][k]; 520*2B stride -> balanced banks for b128
    __shared__ f16 WxS[64][264];
    __shared__ f16 XeS[2][16][264];    // Xe double buffer
    __shared__ f16 HS[16][520];
    __shared__ int sGrp[2];

    const int tid  = threadIdx.x;
    const int wave = tid >> 6, lane = tid & 63;
    const int lrow = lane & 15, lhi = lane >> 4;
    const int gg = lane & 3;           // gate id this lane will own
    const int uu = (lane >> 2) & 3;    // local unit within wave

    // ---- self-assembly: group = physical XCD, slot = claim order ----
    if (tid == 0) {
        uint32_t xcc;
        asm volatile("s_getreg_b32 %0, hwreg(HW_REG_XCC_ID)" : "=s"(xcc));
        int grp = (int)(xcc & 7);
        sGrp[0] = grp;
        sGrp[1] = atomicAdd(&sync[256 + grp * 32], 1);
    }
    __syncthreads();
    const int g  = sGrp[0];
    const int s  = sGrp[1] & 31;
    const int b0 = g * GROWS;
    const int c0 = s * 64;
    const int j0 = s * 16;
    int* fl = sync + g * NSLICE;       // this group's exclusive flag line

    // ---- one-time staging ----
    #pragma unroll
    for (int r = 0; r < 16; r++) {       // Wh slice: 64 x 512 fp16 (64 KB)
        int id = tid + r * 256;
        int row = id >> 6, ko = (id & 63) * 8;
        *(half8*)&WhS[row][ko] = *(const half8*)(WhT + (size_t)(c0 + row) * NH + ko);
    }
    #pragma unroll
    for (int r = 0; r < 8; r++) {        // Wx slice: 64 x 256 fp16 (32 KB)
        int id = tid + r * 256;
        int row = id >> 5, ko = (id & 31) * 8;
        *(half8*)&WxS[row][ko] = *(const half8*)(WxT + (size_t)(c0 + row) * EMB + ko);
    }
    // C in a register: this lane owns (batch b0+4*lhi+gg, unit j0+wave*4+uu)
    float cReg = C0[(size_t)(b0 + 4 * lhi + gg) * NH + j0 + wave * 4 + uu];
    const float bv = bias[c0 + wave * 16 + lrow];

    // Xe prefetch helper: gather E rows for step t into slot
    auto prefetch_xe = [&](int t, int slot) {
        #pragma unroll
        for (int r = 0; r < 4; r++) {
            int id = tid + r * 256;          // 0..1023
            int row = id >> 6, k4 = id & 63; // row 0..15, float4 idx 0..63
            int xv = X[(size_t)(b0 + row) * TSEQ + t];
            float4v e = *(const float4v*)(E + (size_t)xv * EMB + k4 * 4);
            half4v h; h[0] = (f16)e[0]; h[1] = (f16)e[1]; h[2] = (f16)e[2]; h[3] = (f16)e[3];
            *(half4v*)&XeS[slot][row][k4 * 4] = h;
        }
    };

    float4v acc0, acc1, acc2, acc3;
    auto mfma_wx = [&](int slot) {       // acc = Xe[slot] @ WxS   (8 MFMAs, 4 chains)
        acc0 = (float4v)0.f; acc1 = (float4v)0.f;
        acc2 = (float4v)0.f; acc3 = (float4v)0.f;
        const f16(*xp)[264] = XeS[slot];
        #pragma unroll
        for (int kk = 0; kk < EMB; kk += 128) {
            half8 a0 = *(const half8*)&xp[lrow][kk      + lhi * 8];
            half8 w0 = *(const half8*)&WxS[wave * 16 + lrow][kk      + lhi * 8];
            half8 a1 = *(const half8*)&xp[lrow][kk + 32 + lhi * 8];
            half8 w1 = *(const half8*)&WxS[wave * 16 + lrow][kk + 32 + lhi * 8];
            half8 a2 = *(const half8*)&xp[lrow][kk + 64 + lhi * 8];
            half8 w2 = *(const half8*)&WxS[wave * 16 + lrow][kk + 64 + lhi * 8];
            half8 a3 = *(const half8*)&xp[lrow][kk + 96 + lhi * 8];
            half8 w3 = *(const half8*)&WxS[wave * 16 + lrow][kk + 96 + lhi * 8];
            acc0 = __builtin_amdgcn_mfma_f32_16x16x32_f16(a0, w0, acc0, 0, 0, 0);
            acc1 = __builtin_amdgcn_mfma_f32_16x16x32_f16(a1, w1, acc1, 0, 0, 0);
            acc2 = __builtin_amdgcn_mfma_f32_16x16x32_f16(a2, w2, acc2, 0, 0, 0);
            acc3 = __builtin_amdgcn_mfma_f32_16x16x32_f16(a3, w3, acc3, 0, 0, 0);
        }
    };

    prefetch_xe(0, 0);
    __syncthreads();
    mfma_wx(0);                          // pre-acc for t=0
    prefetch_xe(1, 1);

    for (int t = 0; t < TSEQ; t++) {
        // ---- wait until every block in the group has published H_t (L2 poll) ----
        if (wave == 0) {
            uint64_t fap = (uint64_t)(fl + (lane & 31));
            int f;
            do {
                GLOAD32_SC0(f, fap);
                WAITVM0();
                if (lane >= 32) f = 0x7fffffff;
            } while (__all(f >= t) == 0);
        }
        __syncthreads();

        // ---- stage H_t (16 rows x 512) into LDS via sc0 L2-coherent loads ----
        {
            const f16* hsrcp = (t & 1) ? Hb1 : Hb0;
            uint64_t hv0, hv1, hv2, hv3, hv4, hv5, hv6, hv7;
#define LDH(rr, vv) { const int id_ = tid + rr * 256; const int row_ = id_ >> 7, qc_ = id_ & 127; \
            uint64_t ap_ = (uint64_t)(hsrcp + (size_t)(b0 + row_) * NH + qc_ * 4); GLOAD64_SC0(vv, ap_); }
            LDH(0, hv0) LDH(1, hv1) LDH(2, hv2) LDH(3, hv3)
            LDH(4, hv4) LDH(5, hv5) LDH(6, hv6) LDH(7, hv7)
#undef LDH
            WAITVM0();
            __builtin_amdgcn_sched_barrier(0);
#define STH(rr, vv) { const int id_ = tid + rr * 256; const int row_ = id_ >> 7, qc_ = id_ & 127; \
            *(uint64_t*)((char*)&HS[row_][0] + (size_t)qc_ * 8) = vv; }
            STH(0, hv0) STH(1, hv1) STH(2, hv2) STH(3, hv3)
            STH(4, hv4) STH(5, hv5) STH(6, hv6) STH(7, hv7)
#undef STH
        }
        __syncthreads();

        // ---- gates += H_t @ WhS  (16 MFMAs, 4 chains; acc pre-holds Xe@Wx) ----
        #pragma unroll
        for (int kk = 0; kk < NH; kk += 128) {
            half8 a0 = *(const half8*)&HS[lrow][kk      + lhi * 8];
            half8 w0 = *(const half8*)&WhS[wave * 16 + lrow][kk      + lhi * 8];
            half8 a1 = *(const half8*)&HS[lrow][kk + 32 + lhi * 8];
            half8 w1 = *(const half8*)&WhS[wave * 16 + lrow][kk + 32 + lhi * 8];
            half8 a2 = *(const half8*)&HS[lrow][kk + 64 + lhi * 8];
            half8 w2 = *(const half8*)&WhS[wave * 16 + lrow][kk + 64 + lhi * 8];
            half8 a3 = *(const half8*)&HS[lrow][kk + 96 + lhi * 8];
            half8 w3 = *(const half8*)&WhS[wave * 16 + lrow][kk + 96 + lhi * 8];
            acc0 = __builtin_amdgcn_mfma_f32_16x16x32_f16(a0, w0, acc0, 0, 0, 0);
            acc1 = __builtin_amdgcn_mfma_f32_16x16x32_f16(a1, w1, acc1, 0, 0, 0);
            acc2 = __builtin_amdgcn_mfma_f32_16x16x32_f16(a2, w2, acc2, 0, 0, 0);
            acc3 = __builtin_amdgcn_mfma_f32_16x16x32_f16(a3, w3, acc3, 0, 0, 0);
        }

        // ---- 4-lane butterfly: each lane collects F,I,C,O of its (batch,unit) ----
        // D layout: reg r of lane holds (row=4*lhi+r, col=wave*16+lrow).
        {
            float4v ssum = acc0 + acc1 + acc2 + acc3;
            ssum[0] += bv; ssum[1] += bv; ssum[2] += bv; ssum[3] += bv;
            float sg  = gg == 0 ? ssum[0] : gg == 1 ? ssum[1] : gg == 2 ? ssum[2] : ssum[3]; // ssum[gg]
            float sg1 = gg == 0 ? ssum[1] : gg == 1 ? ssum[0] : gg == 2 ? ssum[3] : ssum[2]; // ssum[gg^1]
            float sg2 = gg == 0 ? ssum[2] : gg == 1 ? ssum[3] : gg == 2 ? ssum[0] : ssum[1]; // ssum[gg^2]
            float sg3 = gg == 0 ? ssum[3] : gg == 1 ? ssum[2] : gg == 2 ? ssum[1] : ssum[0]; // ssum[gg^3]
            float r1 = __shfl_xor(sg1, 1);
            float r2 = __shfl_xor(sg2, 2);
            float r3 = __shfl_xor(sg3, 3);
            float F  = gg == 0 ? sg : gg == 1 ? r1 : gg == 2 ? r2 : r3;
            float I  = gg == 0 ? r1 : gg == 1 ? sg : gg == 2 ? r3 : r2;
            float Cc = gg == 0 ? r2 : gg == 1 ? r3 : gg == 2 ? sg : r1;
            float O  = gg == 0 ? r3 : gg == 1 ? r2 : gg == 2 ? r1 : sg;

            float Hn = sigm(O) * ftanh(cReg);          // OLD C (matches reference)
            cReg = sigm(F) * cReg + sigm(I) * ftanh(Cc);

            // pack col pairs (u even stores {u, u+1}) -> one u32 sc0 store per 2 lanes
            float Hp = __shfl_xor(Hn, 4);
            if ((lane & 4) == 0) {
                union { f16 h[2]; uint32_t u32; } pk;
                pk.h[0] = (f16)Hn; pk.h[1] = (f16)Hp;
                f16* hb = ((t + 1) & 1) ? Hb1 : Hb0;
                const int brow = b0 + 4 * lhi + gg;
                const int jcol = j0 + wave * 4 + uu;
                uint64_t ap = (uint64_t)(hb + (size_t)brow * NH + jcol);
                GSTORE32_SC0(ap, pk.u32);
            }
        }
        WAITVM0();         // drain this wave's sc0 H stores (asm stores invisible to compiler)
        __syncthreads();   // all waves' stores now in L2

        // ---- publish generation flag (exclusive L2 line) ----
        if (tid == 0)
            GSTORE32_SC0((uint64_t)&fl[s], t + 1);

        // ---- hidden in barrier slack: pre-acc Wx-part of t+1, prefetch Xe[t+2] ----
        if (t + 1 < TSEQ) {
            mfma_wx((t + 1) & 1);
            if (t + 2 < TSEQ) prefetch_xe(t + 2, t & 1);
        }
    }
}

// ---------------- out = H @ Whq + bq  (M=128, N=32000, K=512) ----------------
__global__ __launch_bounds__(256) void gemm_out(
    const f16* __restrict__ Hh, const f16* __restrict__ WqT,
    const float* __restrict__ bq, float* __restrict__ out)
{
    __shared__ f16 As[128][40];
    __shared__ f16 BsT[64][40];
    int tid = threadIdx.x, wave = tid >> 6, lane = tid & 63;
    int lrow = lane & 15, lhi = lane >> 4;
    int col0 = blockIdx.x * 64;

    float4v acc[2][4];
    #pragma unroll
    for (int m = 0; m < 2; m++)
        #pragma unroll
        for (int j = 0; j < 4; j++) acc[m][j] = (float4v)0.f;

    int ar = tid >> 1, ako = (tid & 1) * 16;
    int br = tid >> 2, bko = (tid & 3) * 8;
    for (int kk = 0; kk < NH; kk += 32) {
        *(half8*)&As[ar][ako]     = *(const half8*)(Hh + (size_t)ar * NH + kk + ako);
        *(half8*)&As[ar][ako + 8] = *(const half8*)(Hh + (size_t)ar * NH + kk + ako + 8);
        *(half8*)&BsT[br][bko]    = *(const half8*)(WqT + (size_t)(col0 + br) * NH + kk + bko);
        __syncthreads();
        half8 af[2];
        #pragma unroll
        for (int m = 0; m < 2; m++)
            af[m] = *(const half8*)&As[wave * 32 + m * 16 + lrow][lhi * 8];
        #pragma unroll
        for (int j = 0; j < 4; j++) {
            half8 bfr = *(const half8*)&BsT[j * 16 + lrow][lhi * 8];
            #pragma unroll
            for (int m = 0; m < 2; m++)
                acc[m][j] = __builtin_amdgcn_mfma_f32_16x16x32_f16(af[m], bfr, acc[m][j], 0, 0, 0);
        }
        __syncthreads();
    }
    #pragma unroll
    for (int m = 0; m < 2; m++)
        #pragma unroll
        for (int j = 0; j < 4; j++) {
            int col = col0 + j * 16 + lrow;
            float bqv = bq[col];
            #pragma unroll
            for (int r = 0; r < 4; r++) {
                int row = wave * 32 + m * 16 + lhi * 4 + r;
                out[(size_t)row * NCLASS + col] = acc[m][j][r] + bqv;
            }
        }
}

// ---------------- launch ----------------
extern "C" void kernel_launch(void* const* d_in, const int* in_sizes, int n_in,
                              void* d_out, int out_size, void* d_ws, size_t ws_size,
                              hipStream_t stream)
{
    (void)in_sizes; (void)n_in; (void)out_size;
    const int*   X   = (const int*)  d_in[0];
    const float* H0  = (const float*)d_in[1];
    const float* C0  = (const float*)d_in[2];
    const float* E   = (const float*)d_in[3];
    const float* Wxf = (const float*)d_in[4];
    const float* Whf = (const float*)d_in[5];
    const float* bf_ = (const float*)d_in[6];
    const float* Wxi = (const float*)d_in[7];
    const float* Whi = (const float*)d_in[8];
    const float* bi_ = (const float*)d_in[9];
    const float* Wxc = (const float*)d_in[10];
    const float* Whc = (const float*)d_in[11];
    const float* bc_ = (const float*)d_in[12];
    const float* Wxo = (const float*)d_in[13];
    const float* Who = (const float*)d_in[14];
    const float* bo_ = (const float*)d_in[15];
    const float* Whq = (const float*)d_in[16];
    const float* bq  = (const float*)d_in[17];

    char* ws = (char*)d_ws;
    size_t o = 0;
    auto alloc = [&](size_t bytes) {
        size_t r = o;
        o = (o + bytes + 255) & ~(size_t)255;
        return r;
    };
    f16*   WxT  = (f16*)  (ws + alloc((size_t)G4 * EMB * 2));
    f16*   WhT  = (f16*)  (ws + alloc((size_t)G4 * NH * 2));
    float* bias = (float*)(ws + alloc((size_t)G4 * 4));
    f16*   WqT  = (f16*)  (ws + alloc((size_t)NH * NCLASS * 2));
    f16*   Hb0  = (f16*)  (ws + alloc((size_t)BATCH * NH * 2));
    f16*   Hb1  = (f16*)  (ws + alloc((size_t)BATCH * NH * 2));
    int*   sync = (int*)  (ws + alloc(512 * 4));   // [g*32+s] flags, [256+g*32] claims
    if (o > ws_size) return;   // insufficient workspace -> clean validation failure

    pack_wT  <<<(G4 * EMB + 255) / 256, 256, 0, stream>>>(Wxf, Wxi, Wxc, Wxo, WxT, EMB);
    pack_wT  <<<(G4 * NH  + 255) / 256, 256, 0, stream>>>(Whf, Whi, Whc, Who, WhT, NH);
    pack_bias<<<(G4 + 255) / 256,       256, 0, stream>>>(bf_, bi_, bc_, bo_, bias);
    transp_whq<<<(NCLASS / 64) * (NH / 64), 256, 0, stream>>>(Whq, WqT);
    init_h   <<<(BATCH * NH + 255) / 256, 256, 0, stream>>>(H0, Hb0);
    zero_sync<<<1, 256, 0, stream>>>(sync);

    lstm_persist<<<256, 256, 0, stream>>>(X, E, C0, WxT, WhT, bias, Hb0, Hb1, sync);

    // T=256 even -> final H is in Hb0
    gemm_out<<<NCLASS / 64, 256, 0, stream>>>(Hb0, WqT, bq, (float*)d_out);
}

// Round 9
// 666.699 us; speedup vs baseline: 3.7472x; 1.0043x over previous
//
#include <hip/hip_runtime.h>
#include <stdint.h>

#define NCLASS 32000
#define EMB    256
#define NH     512
#define BATCH  128
#define TSEQ   256
#define G4     2048   // 4*NH, gate-interleaved columns: c = 4*j + g (g: 0=f,1=i,2=c,3=o)
#define NGROUP 8      // batch groups == XCDs (16 rows each)
#define NSLICE 32     // blocks per group (64 gate cols each)
#define GROWS  16

typedef _Float16 f16;
typedef _Float16 half8  __attribute__((ext_vector_type(8)));
typedef _Float16 half4v __attribute__((ext_vector_type(4)));
typedef float    float4v __attribute__((ext_vector_type(4)));

__device__ __forceinline__ float sigm(float x) { return 1.f / (1.f + __expf(-x)); }
__device__ __forceinline__ float ftanh(float x) {
    float a = fabsf(x);
    float e = __expf(2.f * a);
    float r = 1.f - 2.f / (e + 1.f);   // tanh(a), stable for large a (e=inf -> 1)
    return copysignf(r, x);
}

// sc0 = L1-bypass, L2-coherent (intra-XCD). Manual vmcnt per rule #18.
#define GLOAD64_SC0(dst, ap) asm volatile("global_load_dwordx2 %0, %1, off sc0" : "=v"(dst) : "v"(ap))
#define GLOAD32_SC0(dst, ap) asm volatile("global_load_dword %0, %1, off sc0" : "=v"(dst) : "v"(ap))
#define GSTORE32_SC0(ap, val) asm volatile("global_store_dword %0, %1, off sc0" :: "v"(ap), "v"(val) : "memory")
#define WAITVM0() asm volatile("s_waitcnt vmcnt(0)" ::: "memory")

// ---------------- packing kernels ----------------

// WT[c][k] = W_gate[k][j]  (transposed + gate-interleaved, fp16), c = 4j+g
__global__ __launch_bounds__(256) void pack_wT(
    const float* __restrict__ Wf, const float* __restrict__ Wi,
    const float* __restrict__ Wc, const float* __restrict__ Wo,
    f16* __restrict__ WT, int K)
{
    int idx = blockIdx.x * 256 + threadIdx.x;          // over G4*K
    if (idx >= G4 * K) return;
    int c = idx / K, k = idx - c * K;
    int j = c >> 2, g = c & 3;
    const float* W = (g == 0) ? Wf : ((g == 1) ? Wi : ((g == 2) ? Wc : Wo));
    WT[idx] = (f16)W[k * NH + j];
}

__global__ __launch_bounds__(256) void pack_bias(
    const float* __restrict__ bf_, const float* __restrict__ bi_,
    const float* __restrict__ bc_, const float* __restrict__ bo_,
    float* __restrict__ br)
{
    int c = blockIdx.x * 256 + threadIdx.x;
    if (c >= G4) return;
    int j = c >> 2, g = c & 3;
    const float* b = (g == 0) ? bf_ : ((g == 1) ? bi_ : ((g == 2) ? bc_ : bo_));
    br[c] = b[j];
}

// WqT[n][k] = (f16)Whq[k][n]  -- tiled transpose through LDS, both sides coalesced
__global__ __launch_bounds__(256) void transp_whq(
    const float* __restrict__ Whq, f16* __restrict__ WqT)
{
    __shared__ f16 T[64][72];
    int tid = threadIdx.x;
    int nb = blockIdx.x % (NCLASS / 64);
    int kb = blockIdx.x / (NCLASS / 64);
    int n0 = nb * 64, k0 = kb * 64;
    #pragma unroll
    for (int r = 0; r < 16; r++) {
        int id = tid + r * 256;            // 0..4095
        int kr = id >> 6, nc = id & 63;
        T[nc][kr] = (f16)Whq[(size_t)(k0 + kr) * NCLASS + n0 + nc];
    }
    __syncthreads();
    #pragma unroll
    for (int r = 0; r < 2; r++) {
        int id = tid + r * 256;            // 0..511
        int nr = id >> 3, kc = (id & 7) * 8;
        *(half8*)&WqT[(size_t)(n0 + nr) * NH + k0 + kc] = *(half8*)&T[nr][kc];
    }
}

__global__ __launch_bounds__(256) void init_h(
    const float* __restrict__ H, f16* __restrict__ Hh)
{
    int i = blockIdx.x * 256 + threadIdx.x;
    if (i >= BATCH * NH) return;
    Hh[i] = (f16)H[i];
}

__global__ void zero_sync(int* s) { s[threadIdx.x] = 0; s[threadIdx.x + 256] = 0; }

// ---------------- persistent LSTM recurrence ----------------
// grid = 256 blocks x 256 threads, 1 block/CU (134 KB LDS => pigeonhole: exactly
// 32 blocks per XCD). Blocks self-assemble into groups by physical XCC_ID, so a
// group's 32 blocks provably share one XCD L2 -> all H/flag exchange uses
// sc0-only accesses (L1 bypass, L2-coherent), never leaving the XCD.
//
// SYNC LAYOUT (the round-4 deadlock fix): per-XCD L2s are NOT coherent, so no
// 128-B cache line may ever be written by two XCDs (dirty-writeback clobbering
// in the IF$ permanently loses flag updates -> deadlock). Layout:
//   sync[g*32 + s]      : generation flag of (group g, slice s) -- group g's 32
//                         flags occupy EXACTLY one exclusive 128-B line.
//   sync[256 + g*32]    : claim counter of group g -- one exclusive line each.
__global__ __launch_bounds__(256) void lstm_persist(
    const int* __restrict__ X, const float* __restrict__ E,
    const float* __restrict__ C0,
    const f16* __restrict__ WxT, const f16* __restrict__ WhT,
    const float* __restrict__ bias,
    f16* __restrict__ Hb0, f16* __restrict__ Hb1,
    int* __restrict__ sync)
{
    __shared__ f16 WhS[64][520];       // [col][k]; 520*2B stride -> balanced banks for b128
    __shared__ f16 WxS[64][264];
    __shared__ f16 XeS[2][16][264];    // Xe double buffer
    __shared__ f16 HS[16][520];
    __shared__ int sGrp[2];

    const int tid  = threadIdx.x;
    const int wave = tid >> 6, lane = tid & 63;
    const int lrow = lane & 15, lhi = lane >> 4;
    const int gg = lane & 3;           // gate id this lane will own
    const int uu = (lane >> 2) & 3;    // local unit within wave

    // ---- self-assembly: group = physical XCD, slot = claim order ----
    if (tid == 0) {
        uint32_t xcc;
        asm volatile("s_getreg_b32 %0, hwreg(HW_REG_XCC_ID)" : "=s"(xcc));
        int grp = (int)(xcc & 7);
        sGrp[0] = grp;
        sGrp[1] = atomicAdd(&sync[256 + grp * 32], 1);
    }
    __syncthreads();
    const int g  = sGrp[0];
    const int s  = sGrp[1] & 31;
    const int b0 = g * GROWS;
    const int c0 = s * 64;
    const int j0 = s * 16;
    int* fl = sync + g * NSLICE;       // this group's exclusive flag line

    // ---- one-time staging ----
    #pragma unroll
    for (int r = 0; r < 16; r++) {       // Wh slice: 64 x 512 fp16 (64 KB)
        int id = tid + r * 256;
        int row = id >> 6, ko = (id & 63) * 8;
        *(half8*)&WhS[row][ko] = *(const half8*)(WhT + (size_t)(c0 + row) * NH + ko);
    }
    #pragma unroll
    for (int r = 0; r < 8; r++) {        // Wx slice: 64 x 256 fp16 (32 KB)
        int id = tid + r * 256;
        int row = id >> 5, ko = (id & 31) * 8;
        *(half8*)&WxS[row][ko] = *(const half8*)(WxT + (size_t)(c0 + row) * EMB + ko);
    }
    // C in a register: this lane owns (batch b0+4*lhi+gg, unit j0+wave*4+uu)
    float cReg = C0[(size_t)(b0 + 4 * lhi + gg) * NH + j0 + wave * 4 + uu];
    const float bv = bias[c0 + wave * 16 + lrow];

    // Xe prefetch helper: gather E rows for step t into slot
    auto prefetch_xe = [&](int t, int slot) {
        #pragma unroll
        for (int r = 0; r < 4; r++) {
            int id = tid + r * 256;          // 0..1023
            int row = id >> 6, k4 = id & 63; // row 0..15, float4 idx 0..63
            int xv = X[(size_t)(b0 + row) * TSEQ + t];
            float4v e = *(const float4v*)(E + (size_t)xv * EMB + k4 * 4);
            half4v h; h[0] = (f16)e[0]; h[1] = (f16)e[1]; h[2] = (f16)e[2]; h[3] = (f16)e[3];
            *(half4v*)&XeS[slot][row][k4 * 4] = h;
        }
    };

    float4v acc0, acc1, acc2, acc3;
    auto mfma_wx = [&](int slot) {       // acc = Xe[slot] @ WxS   (8 MFMAs, 4 chains)
        acc0 = (float4v)0.f; acc1 = (float4v)0.f;
        acc2 = (float4v)0.f; acc3 = (float4v)0.f;
        const f16(*xp)[264] = XeS[slot];
        #pragma unroll
        for (int kk = 0; kk < EMB; kk += 128) {
            half8 a0 = *(const half8*)&xp[lrow][kk      + lhi * 8];
            half8 w0 = *(const half8*)&WxS[wave * 16 + lrow][kk      + lhi * 8];
            half8 a1 = *(const half8*)&xp[lrow][kk + 32 + lhi * 8];
            half8 w1 = *(const half8*)&WxS[wave * 16 + lrow][kk + 32 + lhi * 8];
            half8 a2 = *(const half8*)&xp[lrow][kk + 64 + lhi * 8];
            half8 w2 = *(const half8*)&WxS[wave * 16 + lrow][kk + 64 + lhi * 8];
            half8 a3 = *(const half8*)&xp[lrow][kk + 96 + lhi * 8];
            half8 w3 = *(const half8*)&WxS[wave * 16 + lrow][kk + 96 + lhi * 8];
            acc0 = __builtin_amdgcn_mfma_f32_16x16x32_f16(a0, w0, acc0, 0, 0, 0);
            acc1 = __builtin_amdgcn_mfma_f32_16x16x32_f16(a1, w1, acc1, 0, 0, 0);
            acc2 = __builtin_amdgcn_mfma_f32_16x16x32_f16(a2, w2, acc2, 0, 0, 0);
            acc3 = __builtin_amdgcn_mfma_f32_16x16x32_f16(a3, w3, acc3, 0, 0, 0);
        }
    };

    prefetch_xe(0, 0);
    __syncthreads();
    mfma_wx(0);                          // pre-acc for t=0
    prefetch_xe(1, 1);

    for (int t = 0; t < TSEQ; t++) {
        // ---- wait until every block in the group has published H_t (L2 poll) ----
        if (wave == 0) {
            uint64_t fap = (uint64_t)(fl + (lane & 31));
            int f;
            do {
                GLOAD32_SC0(f, fap);
                WAITVM0();
                if (lane >= 32) f = 0x7fffffff;
            } while (__all(f >= t) == 0);
        }
        __syncthreads();

        // ---- stage H_t (16 rows x 512) into LDS via sc0 L2-coherent loads ----
        {
            const f16* hsrcp = (t & 1) ? Hb1 : Hb0;
            uint64_t hv0, hv1, hv2, hv3, hv4, hv5, hv6, hv7;
#define LDH(rr, vv) { const int id_ = tid + rr * 256; const int row_ = id_ >> 7, qc_ = id_ & 127; \
            uint64_t ap_ = (uint64_t)(hsrcp + (size_t)(b0 + row_) * NH + qc_ * 4); GLOAD64_SC0(vv, ap_); }
            LDH(0, hv0) LDH(1, hv1) LDH(2, hv2) LDH(3, hv3)
            LDH(4, hv4) LDH(5, hv5) LDH(6, hv6) LDH(7, hv7)
#undef LDH
            WAITVM0();
            __builtin_amdgcn_sched_barrier(0);
#define STH(rr, vv) { const int id_ = tid + rr * 256; const int row_ = id_ >> 7, qc_ = id_ & 127; \
            *(uint64_t*)((char*)&HS[row_][0] + (size_t)qc_ * 8) = vv; }
            STH(0, hv0) STH(1, hv1) STH(2, hv2) STH(3, hv3)
            STH(4, hv4) STH(5, hv5) STH(6, hv6) STH(7, hv7)
#undef STH
        }
        __syncthreads();

        // ---- gates += H_t @ WhS  (16 MFMAs, 4 chains; acc pre-holds Xe@Wx) ----
        #pragma unroll
        for (int kk = 0; kk < NH; kk += 128) {
            half8 a0 = *(const half8*)&HS[lrow][kk      + lhi * 8];
            half8 w0 = *(const half8*)&WhS[wave * 16 + lrow][kk      + lhi * 8];
            half8 a1 = *(const half8*)&HS[lrow][kk + 32 + lhi * 8];
            half8 w1 = *(const half8*)&WhS[wave * 16 + lrow][kk + 32 + lhi * 8];
            half8 a2 = *(const half8*)&HS[lrow][kk + 64 + lhi * 8];
            half8 w2 = *(const half8*)&WhS[wave * 16 + lrow][kk + 64 + lhi * 8];
            half8 a3 = *(const half8*)&HS[lrow][kk + 96 + lhi * 8];
            half8 w3 = *(const half8*)&WhS[wave * 16 + lrow][kk + 96 + lhi * 8];
            acc0 = __builtin_amdgcn_mfma_f32_16x16x32_f16(a0, w0, acc0, 0, 0, 0);
            acc1 = __builtin_amdgcn_mfma_f32_16x16x32_f16(a1, w1, acc1, 0, 0, 0);
            acc2 = __builtin_amdgcn_mfma_f32_16x16x32_f16(a2, w2, acc2, 0, 0, 0);
            acc3 = __builtin_amdgcn_mfma_f32_16x16x32_f16(a3, w3, acc3, 0, 0, 0);
        }

        // ---- 4-lane butterfly: each lane collects F,I,C,O of its (batch,unit) ----
        // D layout: reg r of lane holds (row=4*lhi+r, col=wave*16+lrow).
        {
            float4v ssum = acc0 + acc1 + acc2 + acc3;
            ssum[0] += bv; ssum[1] += bv; ssum[2] += bv; ssum[3] += bv;
            float sg  = gg == 0 ? ssum[0] : gg == 1 ? ssum[1] : gg == 2 ? ssum[2] : ssum[3]; // ssum[gg]
            float sg1 = gg == 0 ? ssum[1] : gg == 1 ? ssum[0] : gg == 2 ? ssum[3] : ssum[2]; // ssum[gg^1]
            float sg2 = gg == 0 ? ssum[2] : gg == 1 ? ssum[3] : gg == 2 ? ssum[0] : ssum[1]; // ssum[gg^2]
            float sg3 = gg == 0 ? ssum[3] : gg == 1 ? ssum[2] : gg == 2 ? ssum[1] : ssum[0]; // ssum[gg^3]
            float r1 = __shfl_xor(sg1, 1);
            float r2 = __shfl_xor(sg2, 2);
            float r3 = __shfl_xor(sg3, 3);
            float F  = gg == 0 ? sg : gg == 1 ? r1 : gg == 2 ? r2 : r3;
            float I  = gg == 0 ? r1 : gg == 1 ? sg : gg == 2 ? r3 : r2;
            float Cc = gg == 0 ? r2 : gg == 1 ? r3 : gg == 2 ? sg : r1;
            float O  = gg == 0 ? r3 : gg == 1 ? r2 : gg == 2 ? r1 : sg;

            float Hn = sigm(O) * ftanh(cReg);          // OLD C (matches reference)
            cReg = sigm(F) * cReg + sigm(I) * ftanh(Cc);

            // pack col pairs (u even stores {u, u+1}) -> one u32 sc0 store per 2 lanes
            float Hp = __shfl_xor(Hn, 4);
            if ((lane & 4) == 0) {
                union { f16 h[2]; uint32_t u32; } pk;
                pk.h[0] = (f16)Hn; pk.h[1] = (f16)Hp;
                f16* hb = ((t + 1) & 1) ? Hb1 : Hb0;
                const int brow = b0 + 4 * lhi + gg;
                const int jcol = j0 + wave * 4 + uu;
                uint64_t ap = (uint64_t)(hb + (size_t)brow * NH + jcol);
                GSTORE32_SC0(ap, pk.u32);
            }
        }
        WAITVM0();         // drain this wave's sc0 H stores (asm stores invisible to compiler)
        __syncthreads();   // all waves' stores now in L2

        // ---- publish generation flag (exclusive L2 line) ----
        if (tid == 0)
            GSTORE32_SC0((uint64_t)&fl[s], t + 1);

        // ---- hidden in barrier slack: pre-acc Wx-part of t+1, prefetch Xe[t+2] ----
        if (t + 1 < TSEQ) {
            mfma_wx((t + 1) & 1);
            if (t + 2 < TSEQ) prefetch_xe(t + 2, t & 1);
        }
    }
}

// ---------------- out = H @ Whq + bq  (M=128, N=32000, K=512) ----------------
__global__ __launch_bounds__(256) void gemm_out(
    const f16* __restrict__ Hh, const f16* __restrict__ WqT,
    const float* __restrict__ bq, float* __restrict__ out)
{
    __shared__ f16 As[128][40];
    __shared__ f16 BsT[64][40];
    int tid = threadIdx.x, wave = tid >> 6, lane = tid & 63;
    int lrow = lane & 15, lhi = lane >> 4;
    int col0 = blockIdx.x * 64;

    float4v acc[2][4];
    #pragma unroll
    for (int m = 0; m < 2; m++)
        #pragma unroll
        for (int j = 0; j < 4; j++) acc[m][j] = (float4v)0.f;

    int ar = tid >> 1, ako = (tid & 1) * 16;
    int br = tid >> 2, bko = (tid & 3) * 8;
    for (int kk = 0; kk < NH; kk += 32) {
        *(half8*)&As[ar][ako]     = *(const half8*)(Hh + (size_t)ar * NH + kk + ako);
        *(half8*)&As[ar][ako + 8] = *(const half8*)(Hh + (size_t)ar * NH + kk + ako + 8);
        *(half8*)&BsT[br][bko]    = *(const half8*)(WqT + (size_t)(col0 + br) * NH + kk + bko);
        __syncthreads();
        half8 af[2];
        #pragma unroll
        for (int m = 0; m < 2; m++)
            af[m] = *(const half8*)&As[wave * 32 + m * 16 + lrow][lhi * 8];
        #pragma unroll
        for (int j = 0; j < 4; j++) {
            half8 bfr = *(const half8*)&BsT[j * 16 + lrow][lhi * 8];
            #pragma unroll
            for (int m = 0; m < 2; m++)
                acc[m][j] = __builtin_amdgcn_mfma_f32_16x16x32_f16(af[m], bfr, acc[m][j], 0, 0, 0);
        }
        __syncthreads();
    }
    #pragma unroll
    for (int m = 0; m < 2; m++)
        #pragma unroll
        for (int j = 0; j < 4; j++) {
            int col = col0 + j * 16 + lrow;
            float bqv = bq[col];
            #pragma unroll
            for (int r = 0; r < 4; r++) {
                int row = wave * 32 + m * 16 + lhi * 4 + r;
                out[(size_t)row * NCLASS + col] = acc[m][j][r] + bqv;
            }
        }
}

// ---------------- launch ----------------
extern "C" void kernel_launch(void* const* d_in, const int* in_sizes, int n_in,
                              void* d_out, int out_size, void* d_ws, size_t ws_size,
                              hipStream_t stream)
{
    (void)in_sizes; (void)n_in; (void)out_size;
    const int*   X   = (const int*)  d_in[0];
    const float* H0  = (const float*)d_in[1];
    const float* C0  = (const float*)d_in[2];
    const float* E   = (const float*)d_in[3];
    const float* Wxf = (const float*)d_in[4];
    const float* Whf = (const float*)d_in[5];
    const float* bf_ = (const float*)d_in[6];
    const float* Wxi = (const float*)d_in[7];
    const float* Whi = (const float*)d_in[8];
    const float* bi_ = (const float*)d_in[9];
    const float* Wxc = (const float*)d_in[10];
    const float* Whc = (const float*)d_in[11];
    const float* bc_ = (const float*)d_in[12];
    const float* Wxo = (const float*)d_in[13];
    const float* Who = (const float*)d_in[14];
    const float* bo_ = (const float*)d_in[15];
    const float* Whq = (const float*)d_in[16];
    const float* bq  = (const float*)d_in[17];

    char* ws = (char*)d_ws;
    size_t o = 0;
    auto alloc = [&](size_t bytes) {
        size_t r = o;
        o = (o + bytes + 255) & ~(size_t)255;
        return r;
    };
    f16*   WxT  = (f16*)  (ws + alloc((size_t)G4 * EMB * 2));
    f16*   WhT  = (f16*)  (ws + alloc((size_t)G4 * NH * 2));
    float* bias = (float*)(ws + alloc((size_t)G4 * 4));
    f16*   WqT  = (f16*)  (ws + alloc((size_t)NH * NCLASS * 2));
    f16*   Hb0  = (f16*)  (ws + alloc((size_t)BATCH * NH * 2));
    f16*   Hb1  = (f16*)  (ws + alloc((size_t)BATCH * NH * 2));
    int*   sync = (int*)  (ws + alloc(512 * 4));   // [g*32+s] flags, [256+g*32] claims
    if (o > ws_size) return;   // insufficient workspace -> clean validation failure

    pack_wT  <<<(G4 * EMB + 255) / 256, 256, 0, stream>>>(Wxf, Wxi, Wxc, Wxo, WxT, EMB);
    pack_wT  <<<(G4 * NH  + 255) / 256, 256, 0, stream>>>(Whf, Whi, Whc, Who, WhT, NH);
    pack_bias<<<(G4 + 255) / 256,       256, 0, stream>>>(bf_, bi_, bc_, bo_, bias);
    transp_whq<<<(NCLASS / 64) * (NH / 64), 256, 0, stream>>>(Whq, WqT);
    init_h   <<<(BATCH * NH + 255) / 256, 256, 0, stream>>>(H0, Hb0);
    zero_sync<<<1, 256, 0, stream>>>(sync);

    lstm_persist<<<256, 256, 0, stream>>>(X, E, C0, WxT, WhT, bias, Hb0, Hb1, sync);

    // T=256 even -> final H is in Hb0
    gemm_out<<<NCLASS / 64, 256, 0, stream>>>(Hb0, WqT, bq, (float*)d_out);
}

// Round 10
// 651.720 us; speedup vs baseline: 3.8333x; 1.0230x over previous
//
#include <hip/hip_runtime.h>
#include <stdint.h>

#define NCLASS 32000
#define EMB    256
#define NH     512
#define BATCH  128
#define TSEQ   256
#define G4     2048   // 4*NH, gate-interleaved columns: c = 4*j + g (g: 0=f,1=i,2=c,3=o)
#define NGROUP 8      // batch groups == XCDs (16 rows each)
#define NSLICE 32     // blocks per group (64 gate cols each)
#define GROWS  16

typedef _Float16 f16;
typedef _Float16 half8  __attribute__((ext_vector_type(8)));
typedef _Float16 half4v __attribute__((ext_vector_type(4)));
typedef float    float4v __attribute__((ext_vector_type(4)));

__device__ __forceinline__ float sigm(float x) { return 1.f / (1.f + __expf(-x)); }
__device__ __forceinline__ float ftanh(float x) {
    float a = fabsf(x);
    float e = __expf(2.f * a);
    float r = 1.f - 2.f / (e + 1.f);   // tanh(a), stable for large a (e=inf -> 1)
    return copysignf(r, x);
}

// sc0 = L1-bypass, L2-coherent (intra-XCD). Manual vmcnt per rule #18.
#define GLOAD64_SC0(dst, ap) asm volatile("global_load_dwordx2 %0, %1, off sc0" : "=v"(dst) : "v"(ap))
#define GLOAD32_SC0(dst, ap) asm volatile("global_load_dword %0, %1, off sc0" : "=v"(dst) : "v"(ap))
#define GSTORE32_SC0(ap, val) asm volatile("global_store_dword %0, %1, off sc0" :: "v"(ap), "v"(val) : "memory")
#define WAITVM0() asm volatile("s_waitcnt vmcnt(0)" ::: "memory")

// ---------------- mega-pack: all setup work in ONE launch, branch by block range ----
//  blocks [0,4096)        : WhT[c][k] = Whg[k][j]   (G4 x NH)
//  blocks [4096,6144)     : WxT[c][k] = Wxg[k][j]   (G4 x EMB)
//  blocks [6144,6152)     : bias_r[c] = b_g[j]
//  blocks [6152,6408)     : Hh = (f16)H0
//  block  6408            : zero sync (512 ints)
__global__ __launch_bounds__(256) void mega_pack(
    const float* __restrict__ Wxf, const float* __restrict__ Wxi,
    const float* __restrict__ Wxc, const float* __restrict__ Wxo,
    const float* __restrict__ Whf, const float* __restrict__ Whi,
    const float* __restrict__ Whc, const float* __restrict__ Who,
    const float* __restrict__ bf_, const float* __restrict__ bi_,
    const float* __restrict__ bc_, const float* __restrict__ bo_,
    const float* __restrict__ H0,
    f16* __restrict__ WxT, f16* __restrict__ WhT,
    float* __restrict__ bias, f16* __restrict__ Hh, int* __restrict__ sync)
{
    const int bid = blockIdx.x, tid = threadIdx.x;
    if (bid < 4096) {                              // Wh transpose-pack
        int idx = bid * 256 + tid;                 // over G4*NH
        int c = idx >> 9, k = idx & 511;
        int j = c >> 2, g = c & 3;
        const float* W = (g == 0) ? Whf : ((g == 1) ? Whi : ((g == 2) ? Whc : Who));
        WhT[idx] = (f16)W[k * NH + j];
    } else if (bid < 6144) {                       // Wx transpose-pack
        int idx = (bid - 4096) * 256 + tid;        // over G4*EMB
        int c = idx >> 8, k = idx & 255;
        int j = c >> 2, g = c & 3;
        const float* W = (g == 0) ? Wxf : ((g == 1) ? Wxi : ((g == 2) ? Wxc : Wxo));
        WxT[idx] = (f16)W[k * NH + j];
    } else if (bid < 6152) {                       // bias interleave
        int c = (bid - 6144) * 256 + tid;          // over G4
        int j = c >> 2, g = c & 3;
        const float* b = (g == 0) ? bf_ : ((g == 1) ? bi_ : ((g == 2) ? bc_ : bo_));
        bias[c] = b[j];
    } else if (bid < 6408) {                       // H0 -> fp16
        int i = (bid - 6152) * 256 + tid;          // over BATCH*NH
        Hh[i] = (f16)H0[i];
    } else {                                       // zero sync flags + claim counters
        sync[tid] = 0;
        sync[tid + 256] = 0;
    }
}

// ---------------- persistent LSTM recurrence ----------------
// FROZEN: byte-identical to the twice-verified round-5/round-9 kernel (669/667 us).
// grid = 256 blocks x 256 threads, 1 block/CU (134 KB LDS => pigeonhole: exactly
// 32 blocks per XCD). Blocks self-assemble into groups by physical XCC_ID, so a
// group's 32 blocks provably share one XCD L2 -> all H/flag exchange uses
// sc0-only accesses (L1 bypass, L2-coherent), never leaving the XCD.
//
// SYNC LAYOUT (the round-4 deadlock fix): per-XCD L2s are NOT coherent, so no
// 128-B cache line may ever be written by two XCDs (dirty-writeback clobbering
// in the IF$ permanently loses flag updates -> deadlock). Layout:
//   sync[g*32 + s]      : generation flag of (group g, slice s) -- group g's 32
//                         flags occupy EXACTLY one exclusive 128-B line.
//   sync[256 + g*32]    : claim counter of group g -- one exclusive line each.
__global__ __launch_bounds__(256) void lstm_persist(
    const int* __restrict__ X, const float* __restrict__ E,
    const float* __restrict__ C0,
    const f16* __restrict__ WxT, const f16* __restrict__ WhT,
    const float* __restrict__ bias,
    f16* __restrict__ Hb0, f16* __restrict__ Hb1,
    int* __restrict__ sync)
{
    __shared__ f16 WhS[64][520];       // [col][k]; 520*2B stride -> balanced banks for b128
    __shared__ f16 WxS[64][264];
    __shared__ f16 XeS[2][16][264];    // Xe double buffer
    __shared__ f16 HS[16][520];
    __shared__ int sGrp[2];

    const int tid  = threadIdx.x;
    const int wave = tid >> 6, lane = tid & 63;
    const int lrow = lane & 15, lhi = lane >> 4;
    const int gg = lane & 3;           // gate id this lane will own
    const int uu = (lane >> 2) & 3;    // local unit within wave

    // ---- self-assembly: group = physical XCD, slot = claim order ----
    if (tid == 0) {
        uint32_t xcc;
        asm volatile("s_getreg_b32 %0, hwreg(HW_REG_XCC_ID)" : "=s"(xcc));
        int grp = (int)(xcc & 7);
        sGrp[0] = grp;
        sGrp[1] = atomicAdd(&sync[256 + grp * 32], 1);
    }
    __syncthreads();
    const int g  = sGrp[0];
    const int s  = sGrp[1] & 31;
    const int b0 = g * GROWS;
    const int c0 = s * 64;
    const int j0 = s * 16;
    int* fl = sync + g * NSLICE;       // this group's exclusive flag line

    // ---- one-time staging ----
    #pragma unroll
    for (int r = 0; r < 16; r++) {       // Wh slice: 64 x 512 fp16 (64 KB)
        int id = tid + r * 256;
        int row = id >> 6, ko = (id & 63) * 8;
        *(half8*)&WhS[row][ko] = *(const half8*)(WhT + (size_t)(c0 + row) * NH + ko);
    }
    #pragma unroll
    for (int r = 0; r < 8; r++) {        // Wx slice: 64 x 256 fp16 (32 KB)
        int id = tid + r * 256;
        int row = id >> 5, ko = (id & 31) * 8;
        *(half8*)&WxS[row][ko] = *(const half8*)(WxT + (size_t)(c0 + row) * EMB + ko);
    }
    // C in a register: this lane owns (batch b0+4*lhi+gg, unit j0+wave*4+uu)
    float cReg = C0[(size_t)(b0 + 4 * lhi + gg) * NH + j0 + wave * 4 + uu];
    const float bv = bias[c0 + wave * 16 + lrow];

    // Xe prefetch helper: gather E rows for step t into slot
    auto prefetch_xe = [&](int t, int slot) {
        #pragma unroll
        for (int r = 0; r < 4; r++) {
            int id = tid + r * 256;          // 0..1023
            int row = id >> 6, k4 = id & 63; // row 0..15, float4 idx 0..63
            int xv = X[(size_t)(b0 + row) * TSEQ + t];
            float4v e = *(const float4v*)(E + (size_t)xv * EMB + k4 * 4);
            half4v h; h[0] = (f16)e[0]; h[1] = (f16)e[1]; h[2] = (f16)e[2]; h[3] = (f16)e[3];
            *(half4v*)&XeS[slot][row][k4 * 4] = h;
        }
    };

    float4v acc0, acc1, acc2, acc3;
    auto mfma_wx = [&](int slot) {       // acc = Xe[slot] @ WxS   (8 MFMAs, 4 chains)
        acc0 = (float4v)0.f; acc1 = (float4v)0.f;
        acc2 = (float4v)0.f; acc3 = (float4v)0.f;
        const f16(*xp)[264] = XeS[slot];
        #pragma unroll
        for (int kk = 0; kk < EMB; kk += 128) {
            half8 a0 = *(const half8*)&xp[lrow][kk      + lhi * 8];
            half8 w0 = *(const half8*)&WxS[wave * 16 + lrow][kk      + lhi * 8];
            half8 a1 = *(const half8*)&xp[lrow][kk + 32 + lhi * 8];
            half8 w1 = *(const half8*)&WxS[wave * 16 + lrow][kk + 32 + lhi * 8];
            half8 a2 = *(const half8*)&xp[lrow][kk + 64 + lhi * 8];
            half8 w2 = *(const half8*)&WxS[wave * 16 + lrow][kk + 64 + lhi * 8];
            half8 a3 = *(const half8*)&xp[lrow][kk + 96 + lhi * 8];
            half8 w3 = *(const half8*)&WxS[wave * 16 + lrow][kk + 96 + lhi * 8];
            acc0 = __builtin_amdgcn_mfma_f32_16x16x32_f16(a0, w0, acc0, 0, 0, 0);
            acc1 = __builtin_amdgcn_mfma_f32_16x16x32_f16(a1, w1, acc1, 0, 0, 0);
            acc2 = __builtin_amdgcn_mfma_f32_16x16x32_f16(a2, w2, acc2, 0, 0, 0);
            acc3 = __builtin_amdgcn_mfma_f32_16x16x32_f16(a3, w3, acc3, 0, 0, 0);
        }
    };

    prefetch_xe(0, 0);
    __syncthreads();
    mfma_wx(0);                          // pre-acc for t=0
    prefetch_xe(1, 1);

    for (int t = 0; t < TSEQ; t++) {
        // ---- wait until every block in the group has published H_t (L2 poll) ----
        if (wave == 0) {
            uint64_t fap = (uint64_t)(fl + (lane & 31));
            int f;
            do {
                GLOAD32_SC0(f, fap);
                WAITVM0();
                if (lane >= 32) f = 0x7fffffff;
            } while (__all(f >= t) == 0);
        }
        __syncthreads();

        // ---- stage H_t (16 rows x 512) into LDS via sc0 L2-coherent loads ----
        {
            const f16* hsrcp = (t & 1) ? Hb1 : Hb0;
            uint64_t hv0, hv1, hv2, hv3, hv4, hv5, hv6, hv7;
#define LDH(rr, vv) { const int id_ = tid + rr * 256; const int row_ = id_ >> 7, qc_ = id_ & 127; \
            uint64_t ap_ = (uint64_t)(hsrcp + (size_t)(b0 + row_) * NH + qc_ * 4); GLOAD64_SC0(vv, ap_); }
            LDH(0, hv0) LDH(1, hv1) LDH(2, hv2) LDH(3, hv3)
            LDH(4, hv4) LDH(5, hv5) LDH(6, hv6) LDH(7, hv7)
#undef LDH
            WAITVM0();
            __builtin_amdgcn_sched_barrier(0);
#define STH(rr, vv) { const int id_ = tid + rr * 256; const int row_ = id_ >> 7, qc_ = id_ & 127; \
            *(uint64_t*)((char*)&HS[row_][0] + (size_t)qc_ * 8) = vv; }
            STH(0, hv0) STH(1, hv1) STH(2, hv2) STH(3, hv3)
            STH(4, hv4) STH(5, hv5) STH(6, hv6) STH(7, hv7)
#undef STH
        }
        __syncthreads();

        // ---- gates += H_t @ WhS  (16 MFMAs, 4 chains; acc pre-holds Xe@Wx) ----
        #pragma unroll
        for (int kk = 0; kk < NH; kk += 128) {
            half8 a0 = *(const half8*)&HS[lrow][kk      + lhi * 8];
            half8 w0 = *(const half8*)&WhS[wave * 16 + lrow][kk      + lhi * 8];
            half8 a1 = *(const half8*)&HS[lrow][kk + 32 + lhi * 8];
            half8 w1 = *(const half8*)&WhS[wave * 16 + lrow][kk + 32 + lhi * 8];
            half8 a2 = *(const half8*)&HS[lrow][kk + 64 + lhi * 8];
            half8 w2 = *(const half8*)&WhS[wave * 16 + lrow][kk + 64 + lhi * 8];
            half8 a3 = *(const half8*)&HS[lrow][kk + 96 + lhi * 8];
            half8 w3 = *(const half8*)&WhS[wave * 16 + lrow][kk + 96 + lhi * 8];
            acc0 = __builtin_amdgcn_mfma_f32_16x16x32_f16(a0, w0, acc0, 0, 0, 0);
            acc1 = __builtin_amdgcn_mfma_f32_16x16x32_f16(a1, w1, acc1, 0, 0, 0);
            acc2 = __builtin_amdgcn_mfma_f32_16x16x32_f16(a2, w2, acc2, 0, 0, 0);
            acc3 = __builtin_amdgcn_mfma_f32_16x16x32_f16(a3, w3, acc3, 0, 0, 0);
        }

        // ---- 4-lane butterfly: each lane collects F,I,C,O of its (batch,unit) ----
        // D layout: reg r of lane holds (row=4*lhi+r, col=wave*16+lrow).
        {
            float4v ssum = acc0 + acc1 + acc2 + acc3;
            ssum[0] += bv; ssum[1] += bv; ssum[2] += bv; ssum[3] += bv;
            float sg  = gg == 0 ? ssum[0] : gg == 1 ? ssum[1] : gg == 2 ? ssum[2] : ssum[3]; // ssum[gg]
            float sg1 = gg == 0 ? ssum[1] : gg == 1 ? ssum[0] : gg == 2 ? ssum[3] : ssum[2]; // ssum[gg^1]
            float sg2 = gg == 0 ? ssum[2] : gg == 1 ? ssum[3] : gg == 2 ? ssum[0] : ssum[1]; // ssum[gg^2]
            float sg3 = gg == 0 ? ssum[3] : gg == 1 ? ssum[2] : gg == 2 ? ssum[1] : ssum[0]; // ssum[gg^3]
            float r1 = __shfl_xor(sg1, 1);
            float r2 = __shfl_xor(sg2, 2);
            float r3 = __shfl_xor(sg3, 3);
            float F  = gg == 0 ? sg : gg == 1 ? r1 : gg == 2 ? r2 : r3;
            float I  = gg == 0 ? r1 : gg == 1 ? sg : gg == 2 ? r3 : r2;
            float Cc = gg == 0 ? r2 : gg == 1 ? r3 : gg == 2 ? sg : r1;
            float O  = gg == 0 ? r3 : gg == 1 ? r2 : gg == 2 ? r1 : sg;

            float Hn = sigm(O) * ftanh(cReg);          // OLD C (matches reference)
            cReg = sigm(F) * cReg + sigm(I) * ftanh(Cc);

            // pack col pairs (u even stores {u, u+1}) -> one u32 sc0 store per 2 lanes
            float Hp = __shfl_xor(Hn, 4);
            if ((lane & 4) == 0) {
                union { f16 h[2]; uint32_t u32; } pk;
                pk.h[0] = (f16)Hn; pk.h[1] = (f16)Hp;
                f16* hb = ((t + 1) & 1) ? Hb1 : Hb0;
                const int brow = b0 + 4 * lhi + gg;
                const int jcol = j0 + wave * 4 + uu;
                uint64_t ap = (uint64_t)(hb + (size_t)brow * NH + jcol);
                GSTORE32_SC0(ap, pk.u32);
            }
        }
        WAITVM0();         // drain this wave's sc0 H stores (asm stores invisible to compiler)
        __syncthreads();   // all waves' stores now in L2

        // ---- publish generation flag (exclusive L2 line) ----
        if (tid == 0)
            GSTORE32_SC0((uint64_t)&fl[s], t + 1);

        // ---- hidden in barrier slack: pre-acc Wx-part of t+1, prefetch Xe[t+2] ----
        if (t + 1 < TSEQ) {
            mfma_wx((t + 1) & 1);
            if (t + 2 < TSEQ) prefetch_xe(t + 2, t & 1);
        }
    }
}

// ---------------- out = H @ Whq + bq  (M=128, N=32000, K=512) ----------------
// Round-10: Whq transpose+cvt fused into B staging (reads Whq f32 directly,
// coalesced; scalar-transposes the 32x64 tile into BsT[n][k] f16 in LDS).
// Deletes the transp_whq kernel and the 32 MB WqT round-trip.
__global__ __launch_bounds__(256) void gemm_out(
    const f16* __restrict__ Hh, const float* __restrict__ Whq,
    const float* __restrict__ bq, float* __restrict__ out)
{
    __shared__ f16 As[128][40];
    __shared__ f16 BsT[64][40];
    int tid = threadIdx.x, wave = tid >> 6, lane = tid & 63;
    int lrow = lane & 15, lhi = lane >> 4;
    int col0 = blockIdx.x * 64;

    float4v acc[2][4];
    #pragma unroll
    for (int m = 0; m < 2; m++)
        #pragma unroll
        for (int j = 0; j < 4; j++) acc[m][j] = (float4v)0.f;

    int ar = tid >> 1, ako = (tid & 1) * 16;
    int kq = tid >> 3, n0q = (tid & 7) * 8;        // B-tile: k row 0..31, col offset 0..56
    for (int kk = 0; kk < NH; kk += 32) {
        *(half8*)&As[ar][ako]     = *(const half8*)(Hh + (size_t)ar * NH + kk + ako);
        *(half8*)&As[ar][ako + 8] = *(const half8*)(Hh + (size_t)ar * NH + kk + ako + 8);
        {   // fused transpose+cvt: BsT[n][k] = (f16)Whq[kk+k][col0+n]
            const float* wsrc = Whq + (size_t)(kk + kq) * NCLASS + col0 + n0q;
            float4v w0 = *(const float4v*)(wsrc);
            float4v w1 = *(const float4v*)(wsrc + 4);
            BsT[n0q + 0][kq] = (f16)w0[0]; BsT[n0q + 1][kq] = (f16)w0[1];
            BsT[n0q + 2][kq] = (f16)w0[2]; BsT[n0q + 3][kq] = (f16)w0[3];
            BsT[n0q + 4][kq] = (f16)w1[0]; BsT[n0q + 5][kq] = (f16)w1[1];
            BsT[n0q + 6][kq] = (f16)w1[2]; BsT[n0q + 7][kq] = (f16)w1[3];
        }
        __syncthreads();
        half8 af[2];
        #pragma unroll
        for (int m = 0; m < 2; m++)
            af[m] = *(const half8*)&As[wave * 32 + m * 16 + lrow][lhi * 8];
        #pragma unroll
        for (int j = 0; j < 4; j++) {
            half8 bfr = *(const half8*)&BsT[j * 16 + lrow][lhi * 8];
            #pragma unroll
            for (int m = 0; m < 2; m++)
                acc[m][j] = __builtin_amdgcn_mfma_f32_16x16x32_f16(af[m], bfr, acc[m][j], 0, 0, 0);
        }
        __syncthreads();
    }
    #pragma unroll
    for (int m = 0; m < 2; m++)
        #pragma unroll
        for (int j = 0; j < 4; j++) {
            int col = col0 + j * 16 + lrow;
            float bqv = bq[col];
            #pragma unroll
            for (int r = 0; r < 4; r++) {
                int row = wave * 32 + m * 16 + lhi * 4 + r;
                out[(size_t)row * NCLASS + col] = acc[m][j][r] + bqv;
            }
        }
}

// ---------------- launch ----------------
extern "C" void kernel_launch(void* const* d_in, const int* in_sizes, int n_in,
                              void* d_out, int out_size, void* d_ws, size_t ws_size,
                              hipStream_t stream)
{
    (void)in_sizes; (void)n_in; (void)out_size;
    const int*   X   = (const int*)  d_in[0];
    const float* H0  = (const float*)d_in[1];
    const float* C0  = (const float*)d_in[2];
    const float* E   = (const float*)d_in[3];
    const float* Wxf = (const float*)d_in[4];
    const float* Whf = (const float*)d_in[5];
    const float* bf_ = (const float*)d_in[6];
    const float* Wxi = (const float*)d_in[7];
    const float* Whi = (const float*)d_in[8];
    const float* bi_ = (const float*)d_in[9];
    const float* Wxc = (const float*)d_in[10];
    const float* Whc = (const float*)d_in[11];
    const float* bc_ = (const float*)d_in[12];
    const float* Wxo = (const float*)d_in[13];
    const float* Who = (const float*)d_in[14];
    const float* bo_ = (const float*)d_in[15];
    const float* Whq = (const float*)d_in[16];
    const float* bq  = (const float*)d_in[17];

    char* ws = (char*)d_ws;
    size_t o = 0;
    auto alloc = [&](size_t bytes) {
        size_t r = o;
        o = (o + bytes + 255) & ~(size_t)255;
        return r;
    };
    f16*   WxT  = (f16*)  (ws + alloc((size_t)G4 * EMB * 2));
    f16*   WhT  = (f16*)  (ws + alloc((size_t)G4 * NH * 2));
    float* bias = (float*)(ws + alloc((size_t)G4 * 4));
    f16*   Hb0  = (f16*)  (ws + alloc((size_t)BATCH * NH * 2));
    f16*   Hb1  = (f16*)  (ws + alloc((size_t)BATCH * NH * 2));
    int*   sync = (int*)  (ws + alloc(512 * 4));   // [g*32+s] flags, [256+g*32] claims
    if (o > ws_size) return;   // insufficient workspace -> clean validation failure

    mega_pack<<<6409, 256, 0, stream>>>(Wxf, Wxi, Wxc, Wxo, Whf, Whi, Whc, Who,
                                        bf_, bi_, bc_, bo_, H0,
                                        WxT, WhT, bias, Hb0, sync);

    lstm_persist<<<256, 256, 0, stream>>>(X, E, C0, WxT, WhT, bias, Hb0, Hb1, sync);

    // T=256 even -> final H is in Hb0
    gemm_out<<<NCLASS / 64, 256, 0, stream>>>(Hb0, Whq, bq, (float*)d_out);
}

// Round 11
// 649.404 us; speedup vs baseline: 3.8470x; 1.0036x over previous
//
#include <hip/hip_runtime.h>
#include <stdint.h>

#define NCLASS 32000
#define EMB    256
#define NH     512
#define BATCH  128
#define TSEQ   256
#define G4     2048   // 4*NH, gate-interleaved columns: c = 4*j + g (g: 0=f,1=i,2=c,3=o)
#define NGROUP 8      // batch groups == XCDs (16 rows each)
#define NSLICE 32     // blocks per group (64 gate cols each)
#define GROWS  16

typedef _Float16 f16;
typedef _Float16 half8  __attribute__((ext_vector_type(8)));
typedef _Float16 half4v __attribute__((ext_vector_type(4)));
typedef float    float4v __attribute__((ext_vector_type(4)));

__device__ __forceinline__ float sigm(float x) { return 1.f / (1.f + __expf(-x)); }
__device__ __forceinline__ float ftanh(float x) {
    float a = fabsf(x);
    float e = __expf(2.f * a);
    float r = 1.f - 2.f / (e + 1.f);   // tanh(a), stable for large a (e=inf -> 1)
    return copysignf(r, x);
}

// sc0 = L1-bypass, L2-coherent (intra-XCD). Manual vmcnt per rule #18.
#define GLOAD64_SC0(dst, ap) asm volatile("global_load_dwordx2 %0, %1, off sc0" : "=v"(dst) : "v"(ap))
#define GLOAD32_SC0(dst, ap) asm volatile("global_load_dword %0, %1, off sc0" : "=v"(dst) : "v"(ap))
#define GSTORE32_SC0(ap, val) asm volatile("global_store_dword %0, %1, off sc0" :: "v"(ap), "v"(val) : "memory")
#define WAITVM0() asm volatile("s_waitcnt vmcnt(0)" ::: "memory")

// ---------------- mega-pack v2: ONE launch, LDS-tiled coalesced transposes ----
//  blocks [0,256)    : Wh transpose-pack, 64x64 tiles (g = bid>>6, 8x8 tiles)
//  blocks [256,384)  : Wx transpose-pack, 64x64 tiles (g = (bid-256)>>5, 8x4 tiles)
//  blocks [384,392)  : bias interleave
//  blocks [392,456)  : H0 -> fp16 (float4-vectorized)
//  block  456        : zero sync (512 ints)
__global__ __launch_bounds__(256) void mega_pack(
    const float* __restrict__ Wxf, const float* __restrict__ Wxi,
    const float* __restrict__ Wxc, const float* __restrict__ Wxo,
    const float* __restrict__ Whf, const float* __restrict__ Whi,
    const float* __restrict__ Whc, const float* __restrict__ Who,
    const float* __restrict__ bf_, const float* __restrict__ bi_,
    const float* __restrict__ bc_, const float* __restrict__ bo_,
    const float* __restrict__ H0,
    f16* __restrict__ WxT, f16* __restrict__ WhT,
    float* __restrict__ bias, f16* __restrict__ Hh, int* __restrict__ sync)
{
    __shared__ f16 T[64][72];          // padded: transpose tile, conflict-free
    const int bid = blockIdx.x, tid = threadIdx.x;

    if (bid < 384) {                   // weight transpose-pack (Wh or Wx)
        const float* W; f16* dst; int g, j0, k0, K;
        if (bid < 256) {               // Wh: [NH][NH] -> WhT[c][k], c=4j+g
            g = bid >> 6; int rem = bid & 63;
            j0 = (rem >> 3) * 64; k0 = (rem & 7) * 64; K = NH;
            W = (g == 0) ? Whf : ((g == 1) ? Whi : ((g == 2) ? Whc : Who));
            dst = WhT;
        } else {                       // Wx: [EMB][NH] -> WxT[c][k], c=4j+g
            int r2 = bid - 256;
            g = r2 >> 5; int rem = r2 & 31;
            j0 = (rem >> 2) * 64; k0 = (rem & 3) * 64; K = EMB;
            W = (g == 0) ? Wxf : ((g == 1) ? Wxi : ((g == 2) ? Wxc : Wxo));
            dst = WxT;
        }
        // read phase: coalesced along j (row k0+kr of W, 64 consecutive cols)
        #pragma unroll
        for (int r = 0; r < 16; r++) {
            int id = tid + r * 256;            // 0..4095
            int kr = id >> 6, jc = id & 63;
            T[jc][kr] = (f16)W[(size_t)(k0 + kr) * NH + j0 + jc];
        }
        __syncthreads();
        // write phase: coalesced along k (half8 per 8 k)
        #pragma unroll
        for (int r = 0; r < 2; r++) {
            int id = tid + r * 256;            // 0..511
            int row = id >> 3, kc = (id & 7) * 8;
            int c = 4 * (j0 + row) + g;
            *(half8*)&dst[(size_t)c * K + k0 + kc] = *(half8*)&T[row][kc];
        }
    } else if (bid < 392) {            // bias interleave
        int c = (bid - 384) * 256 + tid;       // over G4
        int j = c >> 2, g = c & 3;
        const float* b = (g == 0) ? bf_ : ((g == 1) ? bi_ : ((g == 2) ? bc_ : bo_));
        bias[c] = b[j];
    } else if (bid < 456) {            // H0 -> fp16, float4-vectorized
        int i = (bid - 392) * 256 + tid;       // over (BATCH*NH)/4
        float4v v = ((const float4v*)H0)[i];
        half4v h; h[0] = (f16)v[0]; h[1] = (f16)v[1]; h[2] = (f16)v[2]; h[3] = (f16)v[3];
        ((half4v*)Hh)[i] = h;
    } else {                           // zero sync flags + claim counters
        sync[tid] = 0;
        sync[tid + 256] = 0;
    }
}

// ---------------- persistent LSTM recurrence ----------------
// FROZEN: byte-identical to the twice-verified round-5/round-9 kernel (669/667 us).
// grid = 256 blocks x 256 threads, 1 block/CU (134 KB LDS => pigeonhole: exactly
// 32 blocks per XCD). Blocks self-assemble into groups by physical XCC_ID, so a
// group's 32 blocks provably share one XCD L2 -> all H/flag exchange uses
// sc0-only accesses (L1 bypass, L2-coherent), never leaving the XCD.
//
// SYNC LAYOUT (the round-4 deadlock fix): per-XCD L2s are NOT coherent, so no
// 128-B cache line may ever be written by two XCDs (dirty-writeback clobbering
// in the IF$ permanently loses flag updates -> deadlock). Layout:
//   sync[g*32 + s]      : generation flag of (group g, slice s) -- group g's 32
//                         flags occupy EXACTLY one exclusive 128-B line.
//   sync[256 + g*32]    : claim counter of group g -- one exclusive line each.
__global__ __launch_bounds__(256) void lstm_persist(
    const int* __restrict__ X, const float* __restrict__ E,
    const float* __restrict__ C0,
    const f16* __restrict__ WxT, const f16* __restrict__ WhT,
    const float* __restrict__ bias,
    f16* __restrict__ Hb0, f16* __restrict__ Hb1,
    int* __restrict__ sync)
{
    __shared__ f16 WhS[64][520];       // [col][k]; 520*2B stride -> balanced banks for b128
    __shared__ f16 WxS[64][264];
    __shared__ f16 XeS[2][16][264];    // Xe double buffer
    __shared__ f16 HS[16][520];
    __shared__ int sGrp[2];

    const int tid  = threadIdx.x;
    const int wave = tid >> 6, lane = tid & 63;
    const int lrow = lane & 15, lhi = lane >> 4;
    const int gg = lane & 3;           // gate id this lane will own
    const int uu = (lane >> 2) & 3;    // local unit within wave

    // ---- self-assembly: group = physical XCD, slot = claim order ----
    if (tid == 0) {
        uint32_t xcc;
        asm volatile("s_getreg_b32 %0, hwreg(HW_REG_XCC_ID)" : "=s"(xcc));
        int grp = (int)(xcc & 7);
        sGrp[0] = grp;
        sGrp[1] = atomicAdd(&sync[256 + grp * 32], 1);
    }
    __syncthreads();
    const int g  = sGrp[0];
    const int s  = sGrp[1] & 31;
    const int b0 = g * GROWS;
    const int c0 = s * 64;
    const int j0 = s * 16;
    int* fl = sync + g * NSLICE;       // this group's exclusive flag line

    // ---- one-time staging ----
    #pragma unroll
    for (int r = 0; r < 16; r++) {       // Wh slice: 64 x 512 fp16 (64 KB)
        int id = tid + r * 256;
        int row = id >> 6, ko = (id & 63) * 8;
        *(half8*)&WhS[row][ko] = *(const half8*)(WhT + (size_t)(c0 + row) * NH + ko);
    }
    #pragma unroll
    for (int r = 0; r < 8; r++) {        // Wx slice: 64 x 256 fp16 (32 KB)
        int id = tid + r * 256;
        int row = id >> 5, ko = (id & 31) * 8;
        *(half8*)&WxS[row][ko] = *(const half8*)(WxT + (size_t)(c0 + row) * EMB + ko);
    }
    // C in a register: this lane owns (batch b0+4*lhi+gg, unit j0+wave*4+uu)
    float cReg = C0[(size_t)(b0 + 4 * lhi + gg) * NH + j0 + wave * 4 + uu];
    const float bv = bias[c0 + wave * 16 + lrow];

    // Xe prefetch helper: gather E rows for step t into slot
    auto prefetch_xe = [&](int t, int slot) {
        #pragma unroll
        for (int r = 0; r < 4; r++) {
            int id = tid + r * 256;          // 0..1023
            int row = id >> 6, k4 = id & 63; // row 0..15, float4 idx 0..63
            int xv = X[(size_t)(b0 + row) * TSEQ + t];
            float4v e = *(const float4v*)(E + (size_t)xv * EMB + k4 * 4);
            half4v h; h[0] = (f16)e[0]; h[1] = (f16)e[1]; h[2] = (f16)e[2]; h[3] = (f16)e[3];
            *(half4v*)&XeS[slot][row][k4 * 4] = h;
        }
    };

    float4v acc0, acc1, acc2, acc3;
    auto mfma_wx = [&](int slot) {       // acc = Xe[slot] @ WxS   (8 MFMAs, 4 chains)
        acc0 = (float4v)0.f; acc1 = (float4v)0.f;
        acc2 = (float4v)0.f; acc3 = (float4v)0.f;
        const f16(*xp)[264] = XeS[slot];
        #pragma unroll
        for (int kk = 0; kk < EMB; kk += 128) {
            half8 a0 = *(const half8*)&xp[lrow][kk      + lhi * 8];
            half8 w0 = *(const half8*)&WxS[wave * 16 + lrow][kk      + lhi * 8];
            half8 a1 = *(const half8*)&xp[lrow][kk + 32 + lhi * 8];
            half8 w1 = *(const half8*)&WxS[wave * 16 + lrow][kk + 32 + lhi * 8];
            half8 a2 = *(const half8*)&xp[lrow][kk + 64 + lhi * 8];
            half8 w2 = *(const half8*)&WxS[wave * 16 + lrow][kk + 64 + lhi * 8];
            half8 a3 = *(const half8*)&xp[lrow][kk + 96 + lhi * 8];
            half8 w3 = *(const half8*)&WxS[wave * 16 + lrow][kk + 96 + lhi * 8];
            acc0 = __builtin_amdgcn_mfma_f32_16x16x32_f16(a0, w0, acc0, 0, 0, 0);
            acc1 = __builtin_amdgcn_mfma_f32_16x16x32_f16(a1, w1, acc1, 0, 0, 0);
            acc2 = __builtin_amdgcn_mfma_f32_16x16x32_f16(a2, w2, acc2, 0, 0, 0);
            acc3 = __builtin_amdgcn_mfma_f32_16x16x32_f16(a3, w3, acc3, 0, 0, 0);
        }
    };

    prefetch_xe(0, 0);
    __syncthreads();
    mfma_wx(0);                          // pre-acc for t=0
    prefetch_xe(1, 1);

    for (int t = 0; t < TSEQ; t++) {
        // ---- wait until every block in the group has published H_t (L2 poll) ----
        if (wave == 0) {
            uint64_t fap = (uint64_t)(fl + (lane & 31));
            int f;
            do {
                GLOAD32_SC0(f, fap);
                WAITVM0();
                if (lane >= 32) f = 0x7fffffff;
            } while (__all(f >= t) == 0);
        }
        __syncthreads();

        // ---- stage H_t (16 rows x 512) into LDS via sc0 L2-coherent loads ----
        {
            const f16* hsrcp = (t & 1) ? Hb1 : Hb0;
            uint64_t hv0, hv1, hv2, hv3, hv4, hv5, hv6, hv7;
#define LDH(rr, vv) { const int id_ = tid + rr * 256; const int row_ = id_ >> 7, qc_ = id_ & 127; \
            uint64_t ap_ = (uint64_t)(hsrcp + (size_t)(b0 + row_) * NH + qc_ * 4); GLOAD64_SC0(vv, ap_); }
            LDH(0, hv0) LDH(1, hv1) LDH(2, hv2) LDH(3, hv3)
            LDH(4, hv4) LDH(5, hv5) LDH(6, hv6) LDH(7, hv7)
#undef LDH
            WAITVM0();
            __builtin_amdgcn_sched_barrier(0);
#define STH(rr, vv) { const int id_ = tid + rr * 256; const int row_ = id_ >> 7, qc_ = id_ & 127; \
            *(uint64_t*)((char*)&HS[row_][0] + (size_t)qc_ * 8) = vv; }
            STH(0, hv0) STH(1, hv1) STH(2, hv2) STH(3, hv3)
            STH(4, hv4) STH(5, hv5) STH(6, hv6) STH(7, hv7)
#undef STH
        }
        __syncthreads();

        // ---- gates += H_t @ WhS  (16 MFMAs, 4 chains; acc pre-holds Xe@Wx) ----
        #pragma unroll
        for (int kk = 0; kk < NH; kk += 128) {
            half8 a0 = *(const half8*)&HS[lrow][kk      + lhi * 8];
            half8 w0 = *(const half8*)&WhS[wave * 16 + lrow][kk      + lhi * 8];
            half8 a1 = *(const half8*)&HS[lrow][kk + 32 + lhi * 8];
            half8 w1 = *(const half8*)&WhS[wave * 16 + lrow][kk + 32 + lhi * 8];
            half8 a2 = *(const half8*)&HS[lrow][kk + 64 + lhi * 8];
            half8 w2 = *(const half8*)&WhS[wave * 16 + lrow][kk + 64 + lhi * 8];
            half8 a3 = *(const half8*)&HS[lrow][kk + 96 + lhi * 8];
            half8 w3 = *(const half8*)&WhS[wave * 16 + lrow][kk + 96 + lhi * 8];
            acc0 = __builtin_amdgcn_mfma_f32_16x16x32_f16(a0, w0, acc0, 0, 0, 0);
            acc1 = __builtin_amdgcn_mfma_f32_16x16x32_f16(a1, w1, acc1, 0, 0, 0);
            acc2 = __builtin_amdgcn_mfma_f32_16x16x32_f16(a2, w2, acc2, 0, 0, 0);
            acc3 = __builtin_amdgcn_mfma_f32_16x16x32_f16(a3, w3, acc3, 0, 0, 0);
        }

        // ---- 4-lane butterfly: each lane collects F,I,C,O of its (batch,unit) ----
        // D layout: reg r of lane holds (row=4*lhi+r, col=wave*16+lrow).
        {
            float4v ssum = acc0 + acc1 + acc2 + acc3;
            ssum[0] += bv; ssum[1] += bv; ssum[2] += bv; ssum[3] += bv;
            float sg  = gg == 0 ? ssum[0] : gg == 1 ? ssum[1] : gg == 2 ? ssum[2] : ssum[3]; // ssum[gg]
            float sg1 = gg == 0 ? ssum[1] : gg == 1 ? ssum[0] : gg == 2 ? ssum[3] : ssum[2]; // ssum[gg^1]
            float sg2 = gg == 0 ? ssum[2] : gg == 1 ? ssum[3] : gg == 2 ? ssum[0] : ssum[1]; // ssum[gg^2]
            float sg3 = gg == 0 ? ssum[3] : gg == 1 ? ssum[2] : gg == 2 ? ssum[1] : ssum[0]; // ssum[gg^3]
            float r1 = __shfl_xor(sg1, 1);
            float r2 = __shfl_xor(sg2, 2);
            float r3 = __shfl_xor(sg3, 3);
            float F  = gg == 0 ? sg : gg == 1 ? r1 : gg == 2 ? r2 : r3;
            float I  = gg == 0 ? r1 : gg == 1 ? sg : gg == 2 ? r3 : r2;
            float Cc = gg == 0 ? r2 : gg == 1 ? r3 : gg == 2 ? sg : r1;
            float O  = gg == 0 ? r3 : gg == 1 ? r2 : gg == 2 ? r1 : sg;

            float Hn = sigm(O) * ftanh(cReg);          // OLD C (matches reference)
            cReg = sigm(F) * cReg + sigm(I) * ftanh(Cc);

            // pack col pairs (u even stores {u, u+1}) -> one u32 sc0 store per 2 lanes
            float Hp = __shfl_xor(Hn, 4);
            if ((lane & 4) == 0) {
                union { f16 h[2]; uint32_t u32; } pk;
                pk.h[0] = (f16)Hn; pk.h[1] = (f16)Hp;
                f16* hb = ((t + 1) & 1) ? Hb1 : Hb0;
                const int brow = b0 + 4 * lhi + gg;
                const int jcol = j0 + wave * 4 + uu;
                uint64_t ap = (uint64_t)(hb + (size_t)brow * NH + jcol);
                GSTORE32_SC0(ap, pk.u32);
            }
        }
        WAITVM0();         // drain this wave's sc0 H stores (asm stores invisible to compiler)
        __syncthreads();   // all waves' stores now in L2

        // ---- publish generation flag (exclusive L2 line) ----
        if (tid == 0)
            GSTORE32_SC0((uint64_t)&fl[s], t + 1);

        // ---- hidden in barrier slack: pre-acc Wx-part of t+1, prefetch Xe[t+2] ----
        if (t + 1 < TSEQ) {
            mfma_wx((t + 1) & 1);
            if (t + 2 < TSEQ) prefetch_xe(t + 2, t & 1);
        }
    }
}

// ---------------- out = H @ Whq + bq  (M=128, N=32000, K=512) ----------------
// Whq transpose+cvt fused into B staging (reads Whq f32 directly, coalesced;
// scalar-transposes the 32x64 tile into BsT[n][k] f16 in LDS). Verified round 10.
__global__ __launch_bounds__(256) void gemm_out(
    const f16* __restrict__ Hh, const float* __restrict__ Whq,
    const float* __restrict__ bq, float* __restrict__ out)
{
    __shared__ f16 As[128][40];
    __shared__ f16 BsT[64][40];
    int tid = threadIdx.x, wave = tid >> 6, lane = tid & 63;
    int lrow = lane & 15, lhi = lane >> 4;
    int col0 = blockIdx.x * 64;

    float4v acc[2][4];
    #pragma unroll
    for (int m = 0; m < 2; m++)
        #pragma unroll
        for (int j = 0; j < 4; j++) acc[m][j] = (float4v)0.f;

    int ar = tid >> 1, ako = (tid & 1) * 16;
    int kq = tid >> 3, n0q = (tid & 7) * 8;        // B-tile: k row 0..31, col offset 0..56
    for (int kk = 0; kk < NH; kk += 32) {
        *(half8*)&As[ar][ako]     = *(const half8*)(Hh + (size_t)ar * NH + kk + ako);
        *(half8*)&As[ar][ako + 8] = *(const half8*)(Hh + (size_t)ar * NH + kk + ako + 8);
        {   // fused transpose+cvt: BsT[n][k] = (f16)Whq[kk+k][col0+n]
            const float* wsrc = Whq + (size_t)(kk + kq) * NCLASS + col0 + n0q;
            float4v w0 = *(const float4v*)(wsrc);
            float4v w1 = *(const float4v*)(wsrc + 4);
            BsT[n0q + 0][kq] = (f16)w0[0]; BsT[n0q + 1][kq] = (f16)w0[1];
            BsT[n0q + 2][kq] = (f16)w0[2]; BsT[n0q + 3][kq] = (f16)w0[3];
            BsT[n0q + 4][kq] = (f16)w1[0]; BsT[n0q + 5][kq] = (f16)w1[1];
            BsT[n0q + 6][kq] = (f16)w1[2]; BsT[n0q + 7][kq] = (f16)w1[3];
        }
        __syncthreads();
        half8 af[2];
        #pragma unroll
        for (int m = 0; m < 2; m++)
            af[m] = *(const half8*)&As[wave * 32 + m * 16 + lrow][lhi * 8];
        #pragma unroll
        for (int j = 0; j < 4; j++) {
            half8 bfr = *(const half8*)&BsT[j * 16 + lrow][lhi * 8];
            #pragma unroll
            for (int m = 0; m < 2; m++)
                acc[m][j] = __builtin_amdgcn_mfma_f32_16x16x32_f16(af[m], bfr, acc[m][j], 0, 0, 0);
        }
        __syncthreads();
    }
    #pragma unroll
    for (int m = 0; m < 2; m++)
        #pragma unroll
        for (int j = 0; j < 4; j++) {
            int col = col0 + j * 16 + lrow;
            float bqv = bq[col];
            #pragma unroll
            for (int r = 0; r < 4; r++) {
                int row = wave * 32 + m * 16 + lhi * 4 + r;
                out[(size_t)row * NCLASS + col] = acc[m][j][r] + bqv;
            }
        }
}

// ---------------- launch ----------------
extern "C" void kernel_launch(void* const* d_in, const int* in_sizes, int n_in,
                              void* d_out, int out_size, void* d_ws, size_t ws_size,
                              hipStream_t stream)
{
    (void)in_sizes; (void)n_in; (void)out_size;
    const int*   X   = (const int*)  d_in[0];
    const float* H0  = (const float*)d_in[1];
    const float* C0  = (const float*)d_in[2];
    const float* E   = (const float*)d_in[3];
    const float* Wxf = (const float*)d_in[4];
    const float* Whf = (const float*)d_in[5];
    const float* bf_ = (const float*)d_in[6];
    const float* Wxi = (const float*)d_in[7];
    const float* Whi = (const float*)d_in[8];
    const float* bi_ = (const float*)d_in[9];
    const float* Wxc = (const float*)d_in[10];
    const float* Whc = (const float*)d_in[11];
    const float* bc_ = (const float*)d_in[12];
    const float* Wxo = (const float*)d_in[13];
    const float* Who = (const float*)d_in[14];
    const float* bo_ = (const float*)d_in[15];
    const float* Whq = (const float*)d_in[16];
    const float* bq  = (const float*)d_in[17];

    char* ws = (char*)d_ws;
    size_t o = 0;
    auto alloc = [&](size_t bytes) {
        size_t r = o;
        o = (o + bytes + 255) & ~(size_t)255;
        return r;
    };
    f16*   WxT  = (f16*)  (ws + alloc((size_t)G4 * EMB * 2));
    f16*   WhT  = (f16*)  (ws + alloc((size_t)G4 * NH * 2));
    float* bias = (float*)(ws + alloc((size_t)G4 * 4));
    f16*   Hb0  = (f16*)  (ws + alloc((size_t)BATCH * NH * 2));
    f16*   Hb1  = (f16*)  (ws + alloc((size_t)BATCH * NH * 2));
    int*   sync = (int*)  (ws + alloc(512 * 4));   // [g*32+s] flags, [256+g*32] claims
    if (o > ws_size) return;   // insufficient workspace -> clean validation failure

    mega_pack<<<457, 256, 0, stream>>>(Wxf, Wxi, Wxc, Wxo, Whf, Whi, Whc, Who,
                                       bf_, bi_, bc_, bo_, H0,
                                       WxT, WhT, bias, Hb0, sync);

    lstm_persist<<<256, 256, 0, stream>>>(X, E, C0, WxT, WhT, bias, Hb0, Hb1, sync);

    // T=256 even -> final H is in Hb0
    gemm_out<<<NCLASS / 64, 256, 0, stream>>>(Hb0, Whq, bq, (float*)d_out);
}